// Round 4
// baseline (4166.172 us; speedup 1.0000x reference)
//
#include <hip/hip_runtime.h>
#include <hip/hip_bf16.h>
#include <math.h>

// Problem constants
#define NL 12
#define NH 12
#define DM 768
#define DH 64
#define TT 512
#define NB 16
#define MR (NB*TT)      // 8192 rows
#define D3 (3*DM)       // 2304
#define D4 (4*DM)       // 3072

typedef __bf16 bf16_t;
typedef __attribute__((ext_vector_type(8))) __bf16 bf16x8;
typedef __attribute__((ext_vector_type(4))) __bf16 bf16x4;
typedef __attribute__((ext_vector_type(4))) float f32x4;
typedef __attribute__((ext_vector_type(16))) float f32x16;
typedef __attribute__((ext_vector_type(4))) unsigned int u32x4;

// ---- async global->LDS, 16B per lane. LDS dst is wave-uniform base; HW writes
// lane i at base + i*16. Global src is per-lane. ----
__device__ __forceinline__ void gload_lds16(const void* g, void* l) {
  __builtin_amdgcn_global_load_lds(
      (const __attribute__((address_space(1))) unsigned int*)g,
      (__attribute__((address_space(3))) unsigned int*)l,
      16, 0, 0);
}

__device__ __forceinline__ unsigned pkbf(float a, float b) {
  unsigned short ua = __builtin_bit_cast(unsigned short, (bf16_t)a);
  unsigned short ub = __builtin_bit_cast(unsigned short, (bf16_t)b);
  return (unsigned)ua | ((unsigned)ub << 16);
}

// ---------------- batched weight transpose + f32->bf16, 64x64 tiles ----------------
__global__ __launch_bounds__(256) void transpose_all(
    const float* __restrict__ wqkv, const float* __restrict__ wo,
    const float* __restrict__ wfc, const float* __restrict__ wproj,
    bf16_t* __restrict__ qkvT, bf16_t* __restrict__ woT,
    bf16_t* __restrict__ fcT, bf16_t* __restrict__ projT,
    int l0, int per_layer_out) {
  const int lay = l0 + blockIdx.z;
  int bid = blockIdx.x;
  const float* in; bf16_t* out; int K, N;
  if (bid < 432) {
    in = wqkv + (size_t)lay * DM * D3;
    out = qkvT + (per_layer_out ? 0 : (size_t)lay * D3 * DM);
    K = DM; N = D3;
  } else if (bid < 576) {
    bid -= 432;
    in = wo + (size_t)lay * DM * DM;
    out = woT + (per_layer_out ? 0 : (size_t)lay * DM * DM);
    K = DM; N = DM;
  } else if (bid < 1152) {
    bid -= 576;
    in = wfc + (size_t)lay * DM * D4;
    out = fcT + (per_layer_out ? 0 : (size_t)lay * D4 * DM);
    K = DM; N = D4;
  } else {
    bid -= 1152;
    in = wproj + (size_t)lay * D4 * DM;
    out = projT + (per_layer_out ? 0 : (size_t)lay * DM * D4);
    K = D4; N = DM;
  }
  const int nx = N >> 6;
  const int n0 = (bid % nx) * 64, k0 = (bid / nx) * 64;
  __shared__ float tile[64][68];
  const int t = threadIdx.x;
  const int rr = t >> 4, cc = (t & 15) * 4;
  #pragma unroll
  for (int it = 0; it < 4; ++it) {
    float4 v = *(const float4*)&in[(size_t)(k0 + rr + it * 16) * N + n0 + cc];
    *(float4*)&tile[rr + it * 16][cc] = v;
  }
  __syncthreads();
  // n = lane: wave reads 64 distinct n -> 2 lanes/bank (free); writes L2-merge.
  const int n = t & 63, kb = (t >> 6) * 16;
  bf16x8 o0, o1;
  #pragma unroll
  for (int j = 0; j < 8; ++j) o0[j] = (bf16_t)tile[kb + j][n];
  #pragma unroll
  for (int j = 0; j < 8; ++j) o1[j] = (bf16_t)tile[kb + 8 + j][n];
  bf16_t* op = out + (size_t)(n0 + n) * K + k0 + kb;
  *(bf16x8*)op = o0;
  *(bf16x8*)(op + 8) = o1;
}

// ---------------- embedding ----------------
__global__ __launch_bounds__(256) void embed_kernel(const int* __restrict__ ids,
                                                    const float* __restrict__ wte,
                                                    const float* __restrict__ wpe,
                                                    float* __restrict__ x) {
  const int row = blockIdx.x;
  const int t = row & (TT - 1);
  const int id = ids[row];
  const int tid = threadIdx.x;
  #pragma unroll
  for (int i = 0; i < 3; ++i) {
    const int c = tid + i * 256;
    x[(size_t)row * DM + c] = wte[(size_t)id * DM + c] + wpe[(size_t)t * DM + c];
  }
}

// ---------------- LayerNorm (f32 in -> bf16 out), one WAVE per row ----------------
__global__ __launch_bounds__(256) void ln_kernel(const float* __restrict__ x,
                                                 const float* __restrict__ w,
                                                 const float* __restrict__ b,
                                                 bf16_t* __restrict__ out) {
  const int lane = threadIdx.x & 63, wv = threadIdx.x >> 6;
  const int row = blockIdx.x * 4 + wv;
  const float* xr = x + (size_t)row * DM;
  const int c = lane * 4;
  float4 v0 = *(const float4*)&xr[c];
  float4 v1 = *(const float4*)&xr[c + 256];
  float4 v2 = *(const float4*)&xr[c + 512];
  float s = v0.x + v0.y + v0.z + v0.w + v1.x + v1.y + v1.z + v1.w
          + v2.x + v2.y + v2.z + v2.w;
  #pragma unroll
  for (int off = 32; off > 0; off >>= 1) s += __shfl_xor(s, off);
  const float mean = s * (1.0f / DM);
  float q = 0.0f;
  q += (v0.x-mean)*(v0.x-mean) + (v0.y-mean)*(v0.y-mean) + (v0.z-mean)*(v0.z-mean) + (v0.w-mean)*(v0.w-mean);
  q += (v1.x-mean)*(v1.x-mean) + (v1.y-mean)*(v1.y-mean) + (v1.z-mean)*(v1.z-mean) + (v1.w-mean)*(v1.w-mean);
  q += (v2.x-mean)*(v2.x-mean) + (v2.y-mean)*(v2.y-mean) + (v2.z-mean)*(v2.z-mean) + (v2.w-mean)*(v2.w-mean);
  #pragma unroll
  for (int off = 32; off > 0; off >>= 1) q += __shfl_xor(q, off);
  const float rs = rsqrtf(q * (1.0f / DM) + 1e-5f);
  bf16_t* o = out + (size_t)row * DM;
  #pragma unroll
  for (int i = 0; i < 3; ++i) {
    const int cc = c + i * 256;
    float4 vv = i == 0 ? v0 : (i == 1 ? v1 : v2);
    float4 ww = *(const float4*)&w[cc];
    float4 bb = *(const float4*)&b[cc];
    bf16x4 ob;
    ob[0] = (bf16_t)((vv.x - mean) * rs * ww.x + bb.x);
    ob[1] = (bf16_t)((vv.y - mean) * rs * ww.y + bb.y);
    ob[2] = (bf16_t)((vv.z - mean) * rs * ww.z + bb.z);
    ob[3] = (bf16_t)((vv.w - mean) * rs * ww.w + bb.w);
    *(bf16x4*)&o[cc] = ob;
  }
}

// =====================================================================
// 256x256 8-phase GEMM (T2 swizzle + T3/T4 counted-vmcnt + T5 setprio)
// C[M][N] = A[M][K] * BT[N][K]^T.  8 waves (2M x 4N), per-wave 128x64.
// LDS 128KB: [slot][mat A/B][half][128x64 bf16]. Half-tiles:
//   A-half h = rows {wr*128 + h*64 .. +64} for wr in 0,1 (128 rows)
//   B-half h = rows {wc*64  + h*32 .. +32} for wc in 0..3 (128 rows)
// Swizzle: LDS(r, chunk) = global(r, chunk ^ (r&7)) (16B chunks), applied
// via pre-swizzled global source (gload_lds writes linearly) + swizzled read.
// Phase reads (quadrant mh,nh) / stage-dst schedule derived so each half-tile
// is overwritten exactly one phase after its last reader; vmcnt(6) at end of
// ph3/ph7 makes all 4 half-tiles of the next slot visible before its reads.
// =====================================================================
#define OFF(S, MAT, H) (((((S)*2 + (MAT))*2) + (H)) * 8192)

#define STAGE(S, MAT, H, T) do {                                                \
    const int _r0 = tid >> 3, _r1 = _r0 + 64, _c = tid & 7;                     \
    const bf16_t *_g0, *_g1;                                                    \
    if ((MAT) == 0) {                                                           \
      _g0 = A + (size_t)(m0 + ((_r0 >> 6) << 7) + (H)*64 + (_r0 & 63)) * Kdim   \
              + (T)*64 + ((_c ^ (_r0 & 7)) << 3);                               \
      _g1 = A + (size_t)(m0 + ((_r1 >> 6) << 7) + (H)*64 + (_r1 & 63)) * Kdim   \
              + (T)*64 + ((_c ^ (_r1 & 7)) << 3);                               \
    } else {                                                                    \
      _g0 = BT + (size_t)(n0 + ((_r0 >> 5) << 6) + (H)*32 + (_r0 & 31)) * Kdim  \
              + (T)*64 + ((_c ^ (_r0 & 7)) << 3);                               \
      _g1 = BT + (size_t)(n0 + ((_r1 >> 5) << 6) + (H)*32 + (_r1 & 31)) * Kdim  \
              + (T)*64 + ((_c ^ (_r1 & 7)) << 3);                               \
    }                                                                           \
    gload_lds16(_g0, &lds[OFF(S, MAT, H) + (w << 9)]);                          \
    gload_lds16(_g1, &lds[OFF(S, MAT, H) + 4096 + (w << 9)]);                   \
  } while (0)

#define RD_A(S, MH) do {                                                        \
    _Pragma("unroll") for (int _mf = 0; _mf < 4; ++_mf) {                       \
      const int _lr = wr * 64 + _mf * 16 + l15;                                 \
      const int _x = _lr & 7;                                                   \
      af[_mf][0] = *(const bf16x8*)&lds[OFF(S,0,MH) + _lr*64 + ((l4 ^ _x) << 3)];        \
      af[_mf][1] = *(const bf16x8*)&lds[OFF(S,0,MH) + _lr*64 + (((4+l4) ^ _x) << 3)];    \
    } } while (0)

#define RD_B(S, NH) do {                                                        \
    _Pragma("unroll") for (int _nf = 0; _nf < 2; ++_nf) {                       \
      const int _lr = wc * 32 + _nf * 16 + l15;                                 \
      const int _x = _lr & 7;                                                   \
      bfr[_nf][0] = *(const bf16x8*)&lds[OFF(S,1,NH) + _lr*64 + ((l4 ^ _x) << 3)];       \
      bfr[_nf][1] = *(const bf16x8*)&lds[OFF(S,1,NH) + _lr*64 + (((4+l4) ^ _x) << 3)];   \
    } } while (0)

#define MM(MH, NH) do {                                                         \
    __builtin_amdgcn_s_setprio(1);                                              \
    _Pragma("unroll") for (int _ks = 0; _ks < 2; ++_ks)                         \
      _Pragma("unroll") for (int _mf = 0; _mf < 4; ++_mf)                       \
        _Pragma("unroll") for (int _nf = 0; _nf < 2; ++_nf)                     \
          acc[(MH)*4+_mf][(NH)*2+_nf] = __builtin_amdgcn_mfma_f32_16x16x32_bf16(\
              af[_mf][_ks], bfr[_nf][_ks], acc[(MH)*4+_mf][(NH)*2+_nf], 0,0,0); \
    __builtin_amdgcn_s_setprio(0);                                              \
  } while (0)

#define BAR()   __builtin_amdgcn_s_barrier()
#define LGKM0() asm volatile("s_waitcnt lgkmcnt(0)" ::: "memory")
#define LGKM8() asm volatile("s_waitcnt lgkmcnt(8)" ::: "memory")
#define VM6()   asm volatile("s_waitcnt vmcnt(6)" ::: "memory")

// EPI: 0 = +bias -> bf16 ; 1 = +bias, exact GELU -> bf16 ; 2 = +bias, += f32 resid
template <int EPI>
__global__ __launch_bounds__(512, 2) void gemm8(const bf16_t* __restrict__ A,
                                                const bf16_t* __restrict__ BT,
                                                const float* __restrict__ bias,
                                                bf16_t* __restrict__ outb,
                                                float* __restrict__ resid,
                                                int Ndim, int Kdim) {
  __shared__ bf16_t lds[65536];   // 128 KB
  const int tid = threadIdx.x, lane = tid & 63, w = tid >> 6;
  const int wr = w >> 2, wc = w & 3;
  const int l15 = lane & 15, l4 = lane >> 4;
  const int m0 = blockIdx.y * 256, n0 = blockIdx.x * 256;
  const int nT = Kdim >> 6, nIter = Kdim >> 7;

  f32x4 acc[8][4] = {};
  bf16x8 af[4][2], bfr[2][2];

  // prologue: slot0 = tile0 (4 half-tiles), slot1 = tile1 (3 of 4; B.h0 staged at ph0)
  STAGE(0, 0, 0, 0); STAGE(0, 1, 0, 0); STAGE(0, 0, 1, 0); STAGE(0, 1, 1, 0);
  asm volatile("s_waitcnt vmcnt(4)" ::: "memory");
  STAGE(1, 0, 0, 1); STAGE(1, 1, 1, 1); STAGE(1, 0, 1, 1);
  asm volatile("s_waitcnt vmcnt(6)" ::: "memory");
  BAR();

  for (int it = 0; it < nIter; ++it) {
    const int t1 = 2 * it + 1;
    int ts0 = 2 * it + 2; if (ts0 >= nT) ts0 -= nT;   // wrap: harmless re-stage
    int ts1 = 2 * it + 3; if (ts1 >= nT) ts1 -= nT;
    // ph0: quadrant (0,0) of slot0 tile
    RD_A(0, 0); RD_B(0, 0); STAGE(1, 1, 0, t1);
    LGKM8(); BAR(); LGKM0(); MM(0, 0); BAR();
    // ph1: (0,1)
    RD_B(0, 1); STAGE(0, 0, 0, ts0);
    BAR(); LGKM0(); MM(0, 1); BAR();
    // ph2: (1,1)
    RD_A(0, 1); STAGE(0, 1, 1, ts0);
    BAR(); LGKM0(); MM(1, 1); BAR();
    // ph3: (1,0) ; vmcnt(6) -> slot1 fully visible for ph4-7
    RD_B(0, 0); STAGE(0, 0, 1, ts0);
    BAR(); LGKM0(); MM(1, 0); VM6(); BAR();
    // ph4: quadrant (0,0) of slot1 tile
    RD_A(1, 0); RD_B(1, 0); STAGE(0, 1, 0, ts0);
    LGKM8(); BAR(); LGKM0(); MM(0, 0); BAR();
    // ph5: (0,1)
    RD_B(1, 1); STAGE(1, 0, 0, ts1);
    BAR(); LGKM0(); MM(0, 1); BAR();
    // ph6: (1,1)
    RD_A(1, 1); STAGE(1, 1, 1, ts1);
    BAR(); LGKM0(); MM(1, 1); BAR();
    // ph7: (1,0) ; vmcnt(6) -> slot0 fully visible for next ph0-3
    RD_B(1, 0); STAGE(1, 0, 1, ts1);
    BAR(); LGKM0(); MM(1, 0); VM6(); BAR();
  }

  // epilogue
  #pragma unroll
  for (int mf = 0; mf < 8; ++mf) {
    #pragma unroll
    for (int nf = 0; nf < 4; ++nf) {
      const int col = n0 + wc * 64 + nf * 16 + l15;
      const float bv = bias[col];
      #pragma unroll
      for (int r = 0; r < 4; ++r) {
        const int row = m0 + wr * 128 + mf * 16 + l4 * 4 + r;
        float v = acc[mf][nf][r] + bv;
        if (EPI == 1) v = 0.5f * v * (1.0f + erff(v * 0.70710678118654752f));
        if (EPI == 2) {
          const size_t idx2 = (size_t)row * Ndim + col;
          resid[idx2] += v;
        } else {
          outb[(size_t)row * Ndim + col] = (bf16_t)v;
        }
      }
    }
  }
}

// ---------------- fused flash attention (unchanged from round 3) ----------------
__global__ __launch_bounds__(512) void attn_kernel(const bf16_t* __restrict__ qkv,
                                                   bf16_t* __restrict__ y) {
  const int qt = blockIdx.x, hh = blockIdx.y, bb = blockIdx.z;
  const int tid = threadIdx.x, lane = tid & 63, w = tid >> 6;
  const int l31 = lane & 31, hiL = lane >> 5;

  __shared__ bf16_t smem[18432];
  bf16_t* Kbuf = smem;
  bf16_t* Vbuf = smem + 8192;

  const bf16_t* kb = qkv + (size_t)(bb * TT) * D3 + DM + hh * 64;
  const bf16_t* vb = qkv + (size_t)(bb * TT) * D3 + 2 * DM + hh * 64;

  const bf16_t* qptr = qkv + (size_t)(bb * TT + qt * 256 + w * 32 + l31) * D3 + hh * 64 + hiL * 8;
  bf16x8 qreg[4];
  #pragma unroll
  for (int ks = 0; ks < 4; ++ks) {
    bf16x8 v = *(const bf16x8*)(qptr + ks * 16);
    #pragma unroll
    for (int j = 0; j < 8; ++j) qreg[ks][j] = (bf16_t)((float)v[j] * 0.125f);
  }

  const int sr = tid >> 3, sc = tid & 7;
  #define ATTN_STAGE(KT, BUF)                                                     \
    {                                                                             \
      gload_lds16(kb + (size_t)((KT) * 64 + sr) * D3 + ((sc ^ (sr & 7)) * 8),     \
                  Kbuf + (BUF) * 4096 + (w << 9));                                \
      bf16x8 tv;                                                                  \
      _Pragma("unroll")                                                           \
      for (int j = 0; j < 8; ++j) tv[j] = vb[(size_t)((KT) * 64 + w * 8 + j) * D3 + lane]; \
      *(bf16x8*)&Vbuf[(BUF) * 4096 + lane * 64 + ((w ^ (lane & 7)) << 3)] = tv;   \
    }

  ATTN_STAGE(0, 0);

  f32x16 o0 = 0.0f, o1 = 0.0f;
  float m = -INFINITY, l = 0.0f;

  for (int kt = 0; kt < 8; ++kt) {
    __syncthreads();
    if (kt < 7) ATTN_STAGE(kt + 1, (kt + 1) & 1);

    const bf16_t* Kb = Kbuf + (kt & 1) * 4096;
    const bf16_t* Vb = Vbuf + (kt & 1) * 4096;

    f32x16 st0 = 0.0f, st1 = 0.0f;
    #pragma unroll
    for (int ks = 0; ks < 4; ++ks) {
      const int ch = (ks * 2 + hiL) ^ (l31 & 7);
      bf16x8 kf0 = *(const bf16x8*)&Kb[l31 * 64 + ch * 8];
      bf16x8 kf1 = *(const bf16x8*)&Kb[(32 + l31) * 64 + ch * 8];
      st0 = __builtin_amdgcn_mfma_f32_32x32x16_bf16(kf0, qreg[ks], st0, 0, 0, 0);
      st1 = __builtin_amdgcn_mfma_f32_32x32x16_bf16(kf1, qreg[ks], st1, 0, 0, 0);
    }

    float tm = fmaxf(st0[0], st1[0]);
    #pragma unroll
    for (int i = 1; i < 16; ++i) tm = fmaxf(tm, fmaxf(st0[i], st1[i]));
    tm = fmaxf(tm, __shfl_xor(tm, 32));
    const float mnew = fmaxf(m, tm);
    const float al = __expf(m - mnew);
    #pragma unroll
    for (int i = 0; i < 16; ++i) st0[i] = __expf(st0[i] - mnew);
    #pragma unroll
    for (int i = 0; i < 16; ++i) st1[i] = __expf(st1[i] - mnew);
    float ps = 0.0f;
    #pragma unroll
    for (int i = 0; i < 16; ++i) ps += st0[i] + st1[i];
    ps += __shfl_xor(ps, 32);
    l = l * al + ps;
    m = mnew;
    #pragma unroll
    for (int i = 0; i < 16; ++i) { o0[i] *= al; o1[i] *= al; }

    #pragma unroll
    for (int g = 0; g < 2; ++g) {
      unsigned u0, u1, u2, u3, u4, u5, u6, u7;
      if (g == 0) {
        u0 = pkbf(st0[0], st0[1]);   u1 = pkbf(st0[2], st0[3]);
        u2 = pkbf(st0[4], st0[5]);   u3 = pkbf(st0[6], st0[7]);
        u4 = pkbf(st0[8], st0[9]);   u5 = pkbf(st0[10], st0[11]);
        u6 = pkbf(st0[12], st0[13]); u7 = pkbf(st0[14], st0[15]);
      } else {
        u0 = pkbf(st1[0], st1[1]);   u1 = pkbf(st1[2], st1[3]);
        u2 = pkbf(st1[4], st1[5]);   u3 = pkbf(st1[6], st1[7]);
        u4 = pkbf(st1[8], st1[9]);   u5 = pkbf(st1[10], st1[11]);
        u6 = pkbf(st1[12], st1[13]); u7 = pkbf(st1[14], st1[15]);
      }
      #pragma unroll
      for (int ks2 = 0; ks2 < 2; ++ks2) {
        const unsigned a0 = ks2 ? u4 : u0, a1 = ks2 ? u5 : u1;
        const unsigned a2 = ks2 ? u6 : u2, a3 = ks2 ? u7 : u3;
        const unsigned own0 = hiL ? a2 : a0, own1 = hiL ? a3 : a1;
        const unsigned snd0 = hiL ? a0 : a2, snd1 = hiL ? a1 : a3;
        const unsigned rcv0 = (unsigned)__shfl_xor((int)snd0, 32);
        const unsigned rcv1 = (unsigned)__shfl_xor((int)snd1, 32);
        u32x4 fw;
        fw[0] = hiL ? rcv0 : own0;
        fw[1] = hiL ? rcv1 : own1;
        fw[2] = hiL ? own0 : rcv0;
        fw[3] = hiL ? own1 : rcv1;
        const bf16x8 pa = __builtin_bit_cast(bf16x8, fw);
        const int chv = (g * 4 + ks2 * 2 + hiL) ^ (l31 & 7);
        bf16x8 vf0 = *(const bf16x8*)&Vb[l31 * 64 + chv * 8];
        bf16x8 vf1 = *(const bf16x8*)&Vb[(32 + l31) * 64 + chv * 8];
        o0 = __builtin_amdgcn_mfma_f32_32x32x16_bf16(vf0, pa, o0, 0, 0, 0);
        o1 = __builtin_amdgcn_mfma_f32_32x32x16_bf16(vf1, pa, o1, 0, 0, 0);
      }
    }
  }

  __syncthreads();
  const float rl = 1.0f / l;
  bf16_t* Ob = smem;
  #pragma unroll
  for (int reg = 0; reg < 16; ++reg) {
    const int drow = (reg & 3) + 8 * (reg >> 2) + 4 * hiL;
    Ob[(w * 32 + l31) * 72 + drow]      = (bf16_t)(o0[reg] * rl);
    Ob[(w * 32 + l31) * 72 + 32 + drow] = (bf16_t)(o1[reg] * rl);
  }
  __syncthreads();
  const int qrow = tid >> 1, half = tid & 1;
  bf16_t* yp = y + (size_t)(bb * TT + qt * 256 + qrow) * DM + hh * 64 + half * 32;
  const bf16_t* obp = &Ob[qrow * 72 + half * 32];
  *(bf16x8*)(yp)      = *(const bf16x8*)(obp);
  *(bf16x8*)(yp + 8)  = *(const bf16x8*)(obp + 8);
  *(bf16x8*)(yp + 16) = *(const bf16x8*)(obp + 16);
  *(bf16x8*)(yp + 24) = *(const bf16x8*)(obp + 24);
  #undef ATTN_STAGE
}

// ---------------- final LN (CLS) + dense + tanh -> pooled ----------------
__global__ __launch_bounds__(256) void pooled_kernel(const float* __restrict__ x,
                                                     const float* __restrict__ lnw,
                                                     const float* __restrict__ lnb,
                                                     const float* __restrict__ dw,
                                                     const float* __restrict__ db,
                                                     float* __restrict__ pooled) {
  const int bb = blockIdx.y, tid = threadIdx.x;
  const int lane = tid & 63, wv = tid >> 6;
  const float* xr = x + (size_t)(bb * TT) * DM;
  float v0 = xr[tid], v1 = xr[tid + 256], v2 = xr[tid + 512];
  __shared__ float red[8];
  __shared__ float lx[DM];
  float s = v0 + v1 + v2;
  #pragma unroll
  for (int off = 32; off > 0; off >>= 1) s += __shfl_down(s, off);
  if (lane == 0) red[wv] = s;
  __syncthreads();
  const float mean = (red[0] + red[1] + red[2] + red[3]) * (1.0f / DM);
  const float d0 = v0 - mean, d1 = v1 - mean, d2 = v2 - mean;
  float q = d0 * d0 + d1 * d1 + d2 * d2;
  #pragma unroll
  for (int off = 32; off > 0; off >>= 1) q += __shfl_down(q, off);
  __syncthreads();
  if (lane == 0) red[wv] = q;
  __syncthreads();
  const float var = (red[0] + red[1] + red[2] + red[3]) * (1.0f / DM);
  const float rs = rsqrtf(var + 1e-5f);

  lx[tid]       = d0 * rs * lnw[tid] + lnb[tid];
  lx[tid + 256] = d1 * rs * lnw[tid + 256] + lnb[tid + 256];
  lx[tid + 512] = d2 * rs * lnw[tid + 512] + lnb[tid + 512];
  __syncthreads();

  const int j = blockIdx.x * 64 + (tid >> 2), sl = tid & 3;
  const int k0 = sl * 192;
  float acc = 0.0f;
  #pragma unroll 4
  for (int k = k0; k < k0 + 192; ++k) acc += lx[k] * dw[(size_t)k * DM + j];
  acc += __shfl_xor(acc, 1);
  acc += __shfl_xor(acc, 2);
  if (sl == 0) pooled[bb * DM + j] = tanhf(acc + db[j]);
}

// ---------------- logits ----------------
__global__ void logits_kernel(const float* __restrict__ pooled,
                              const float* __restrict__ hw,
                              const float* __restrict__ hb,
                              float* __restrict__ out) {
  const int tid = threadIdx.x;
  if (tid < 32) {
    const int bb = tid >> 1, c = tid & 1;
    float acc = hb[c];
    for (int k = 0; k < DM; ++k) acc += pooled[bb * DM + k] * hw[k * 2 + c];
    out[bb * 2 + c] = acc;
  }
}

extern "C" void kernel_launch(void* const* d_in, const int* in_sizes, int n_in,
                              void* d_out, int out_size, void* d_ws, size_t ws_size,
                              hipStream_t stream) {
  const int*   ids   = (const int*)d_in[0];
  const float* wte   = (const float*)d_in[3];
  const float* wpe   = (const float*)d_in[4];
  const float* ln1w  = (const float*)d_in[5];
  const float* ln1b  = (const float*)d_in[6];
  const float* wqkv  = (const float*)d_in[7];
  const float* bqkv  = (const float*)d_in[8];
  const float* wo    = (const float*)d_in[9];
  const float* bo    = (const float*)d_in[10];
  const float* ln2w  = (const float*)d_in[11];
  const float* ln2b  = (const float*)d_in[12];
  const float* wfc   = (const float*)d_in[13];
  const float* bfc   = (const float*)d_in[14];
  const float* wproj = (const float*)d_in[15];
  const float* bproj = (const float*)d_in[16];
  const float* lnfw  = (const float*)d_in[17];
  const float* lnfb  = (const float*)d_in[18];
  const float* dw    = (const float*)d_in[19];
  const float* db    = (const float*)d_in[20];
  const float* hw    = (const float*)d_in[21];
  const float* hb    = (const float*)d_in[22];
  float* out = (float*)d_out;

  const size_t NEED_FULL = 308330496ULL;
  const bool full = ws_size >= NEED_FULL;

  char* ws = (char*)d_ws;
  size_t off = 0;
  auto alloc = [&](size_t bytes) -> void* {
    void* p = ws + off;
    off += (bytes + 255) & ~(size_t)255;
    return p;
  };
  float*  x      = (float*)alloc((size_t)MR * DM * 4);
  bf16_t* h      = (bf16_t*)alloc((size_t)MR * DM * 2);
  bf16_t* qkvb   = (bf16_t*)alloc((size_t)MR * D3 * 2);
  bf16_t* yb     = (bf16_t*)alloc((size_t)MR * DM * 2);
  bf16_t* ub     = (bf16_t*)alloc((size_t)MR * D4 * 2);
  float*  pooled = (float*)alloc((size_t)NB * DM * 4);
  const size_t wmul = full ? NL : 1;
  bf16_t* wqkvT  = (bf16_t*)alloc((size_t)D3 * DM * 2 * wmul);
  bf16_t* woT    = (bf16_t*)alloc((size_t)DM * DM * 2 * wmul);
  bf16_t* wfcT   = (bf16_t*)alloc((size_t)D4 * DM * 2 * wmul);
  bf16_t* wprojT = (bf16_t*)alloc((size_t)DM * D4 * 2 * wmul);

  embed_kernel<<<MR, 256, 0, stream>>>(ids, wte, wpe, x);

  if (full) {
    transpose_all<<<dim3(1728, 1, NL), 256, 0, stream>>>(
        wqkv, wo, wfc, wproj, wqkvT, woT, wfcT, wprojT, 0, 0);
  }

  for (int l = 0; l < NL; ++l) {
    if (!full) {
      transpose_all<<<dim3(1728, 1, 1), 256, 0, stream>>>(
          wqkv, wo, wfc, wproj, wqkvT, woT, wfcT, wprojT, l, 1);
    }
    bf16_t* qkvT_l = wqkvT + (full ? (size_t)l * D3 * DM : 0);
    bf16_t* woT_l  = woT   + (full ? (size_t)l * DM * DM : 0);
    bf16_t* fcT_l  = wfcT  + (full ? (size_t)l * D4 * DM : 0);
    bf16_t* prT_l  = wprojT+ (full ? (size_t)l * DM * D4 : 0);

    ln_kernel<<<MR / 4, 256, 0, stream>>>(x, ln1w + l * DM, ln1b + l * DM, h);
    gemm8<0><<<dim3(D3 / 256, MR / 256), 512, 0, stream>>>(
        h, qkvT_l, bqkv + (size_t)l * D3, qkvb, nullptr, D3, DM);
    attn_kernel<<<dim3(TT / 256, NH, NB), 512, 0, stream>>>(qkvb, yb);
    gemm8<2><<<dim3(DM / 256, MR / 256), 512, 0, stream>>>(
        yb, woT_l, bo + (size_t)l * DM, nullptr, x, DM, DM);
    ln_kernel<<<MR / 4, 256, 0, stream>>>(x, ln2w + l * DM, ln2b + l * DM, h);
    gemm8<1><<<dim3(D4 / 256, MR / 256), 512, 0, stream>>>(
        h, fcT_l, bfc + (size_t)l * D4, ub, nullptr, D4, DM);
    gemm8<2><<<dim3(DM / 256, MR / 256), 512, 0, stream>>>(
        ub, prT_l, bproj + (size_t)l * DM, nullptr, x, DM, D4);
  }

  pooled_kernel<<<dim3(12, NB), 256, 0, stream>>>(x, lnfw, lnfb, dw, db, pooled);
  logits_kernel<<<1, 64, 0, stream>>>(pooled, hw, hb, out);
}

// Round 5
// 3894.247 us; speedup vs baseline: 1.0698x; 1.0698x over previous
//
#include <hip/hip_runtime.h>
#include <hip/hip_bf16.h>
#include <math.h>

// Problem constants
#define NL 12
#define NH 12
#define DM 768
#define DH 64
#define TT 512
#define NB 16
#define MR (NB*TT)      // 8192 rows
#define D3 (3*DM)       // 2304
#define D4 (4*DM)       // 3072

typedef __bf16 bf16_t;
typedef __attribute__((ext_vector_type(8))) __bf16 bf16x8;
typedef __attribute__((ext_vector_type(4))) __bf16 bf16x4;
typedef __attribute__((ext_vector_type(4))) float f32x4;
typedef __attribute__((ext_vector_type(16))) float f32x16;
typedef __attribute__((ext_vector_type(4))) unsigned int u32x4;

// ---- async global->LDS, 16B per lane. LDS dst is wave-uniform base; HW writes
// lane i at base + i*16. Global src is per-lane. ----
__device__ __forceinline__ void gload_lds16(const void* g, void* l) {
  __builtin_amdgcn_global_load_lds(
      (const __attribute__((address_space(1))) unsigned int*)g,
      (__attribute__((address_space(3))) unsigned int*)l,
      16, 0, 0);
}

__device__ __forceinline__ unsigned pkbf(float a, float b) {
  unsigned short ua = __builtin_bit_cast(unsigned short, (bf16_t)a);
  unsigned short ub = __builtin_bit_cast(unsigned short, (bf16_t)b);
  return (unsigned)ua | ((unsigned)ub << 16);
}

// ---------------- batched weight transpose + f32->bf16 into BLOCKED layout ----------------
// Output layout: [ktile t][nb][row r 0..255][chunk c 0..7][8 bf16], where the stored
// chunk at position c holds original k-chunk (c ^ (r&7)) of k-tile t — i.e. the
// exact pre-swizzled image gemm8's B-STAGE wants (linear source, XOR read).
__global__ __launch_bounds__(256) void transpose_all(
    const float* __restrict__ wqkv, const float* __restrict__ wo,
    const float* __restrict__ wfc, const float* __restrict__ wproj,
    bf16_t* __restrict__ qkvT, bf16_t* __restrict__ woT,
    bf16_t* __restrict__ fcT, bf16_t* __restrict__ projT,
    int l0, int per_layer_out) {
  const int lay = l0 + blockIdx.z;
  int bid = blockIdx.x;
  const float* in; bf16_t* out; int K, N;
  if (bid < 432) {
    in = wqkv + (size_t)lay * DM * D3;
    out = qkvT + (per_layer_out ? 0 : (size_t)lay * D3 * DM);
    K = DM; N = D3;
  } else if (bid < 576) {
    bid -= 432;
    in = wo + (size_t)lay * DM * DM;
    out = woT + (per_layer_out ? 0 : (size_t)lay * DM * DM);
    K = DM; N = DM;
  } else if (bid < 1152) {
    bid -= 576;
    in = wfc + (size_t)lay * DM * D4;
    out = fcT + (per_layer_out ? 0 : (size_t)lay * D4 * DM);
    K = DM; N = D4;
  } else {
    bid -= 1152;
    in = wproj + (size_t)lay * D4 * DM;
    out = projT + (per_layer_out ? 0 : (size_t)lay * DM * D4);
    K = D4; N = DM;
  }
  const int nx = N >> 6;
  const int n0 = (bid % nx) * 64, k0 = (bid / nx) * 64;
  __shared__ float tile[64][68];
  const int t = threadIdx.x;
  const int rr = t >> 4, cc = (t & 15) * 4;
  #pragma unroll
  for (int it = 0; it < 4; ++it) {
    float4 v = *(const float4*)&in[(size_t)(k0 + rr + it * 16) * N + n0 + cc];
    *(float4*)&tile[rr + it * 16][cc] = v;
  }
  __syncthreads();
  // n = lane: conflict-free column read (2 lanes/bank); blocked write = per-wave
  // contiguous 2KB window -> L2-coalesced.
  const int n = t & 63, kb = (t >> 6) * 16;
  bf16x8 o0, o1;
  #pragma unroll
  for (int j = 0; j < 8; ++j) o0[j] = (bf16_t)tile[kb + j][n];
  #pragma unroll
  for (int j = 0; j < 8; ++j) o1[j] = (bf16_t)tile[kb + 8 + j][n];
  const int rg = n0 + n;
  const int nb = rg >> 8, r = rg & 255;
  const int nbN = N >> 8;
  const int x = n & 7;
  const int c0 = kb >> 3;                  // 0,2,4,6
  bf16_t* base = out + (((size_t)(k0 >> 6) * nbN + nb) * 256 + r) * 64;
  *(bf16x8*)(base + (((c0)     ^ x) << 3)) = o0;
  *(bf16x8*)(base + (((c0 + 1) ^ x) << 3)) = o1;
}

// ---------------- embedding ----------------
__global__ __launch_bounds__(256) void embed_kernel(const int* __restrict__ ids,
                                                    const float* __restrict__ wte,
                                                    const float* __restrict__ wpe,
                                                    float* __restrict__ x) {
  const int row = blockIdx.x;
  const int t = row & (TT - 1);
  const int id = ids[row];
  const int tid = threadIdx.x;
  #pragma unroll
  for (int i = 0; i < 3; ++i) {
    const int c = tid + i * 256;
    x[(size_t)row * DM + c] = wte[(size_t)id * DM + c] + wpe[(size_t)t * DM + c];
  }
}

// ---------------- LayerNorm (f32 in -> bf16 out), one WAVE per row ----------------
__global__ __launch_bounds__(256) void ln_kernel(const float* __restrict__ x,
                                                 const float* __restrict__ w,
                                                 const float* __restrict__ b,
                                                 bf16_t* __restrict__ out) {
  const int lane = threadIdx.x & 63, wv = threadIdx.x >> 6;
  const int row = blockIdx.x * 4 + wv;
  const float* xr = x + (size_t)row * DM;
  const int c = lane * 4;
  float4 v0 = *(const float4*)&xr[c];
  float4 v1 = *(const float4*)&xr[c + 256];
  float4 v2 = *(const float4*)&xr[c + 512];
  float s = v0.x + v0.y + v0.z + v0.w + v1.x + v1.y + v1.z + v1.w
          + v2.x + v2.y + v2.z + v2.w;
  #pragma unroll
  for (int off = 32; off > 0; off >>= 1) s += __shfl_xor(s, off);
  const float mean = s * (1.0f / DM);
  float q = 0.0f;
  q += (v0.x-mean)*(v0.x-mean) + (v0.y-mean)*(v0.y-mean) + (v0.z-mean)*(v0.z-mean) + (v0.w-mean)*(v0.w-mean);
  q += (v1.x-mean)*(v1.x-mean) + (v1.y-mean)*(v1.y-mean) + (v1.z-mean)*(v1.z-mean) + (v1.w-mean)*(v1.w-mean);
  q += (v2.x-mean)*(v2.x-mean) + (v2.y-mean)*(v2.y-mean) + (v2.z-mean)*(v2.z-mean) + (v2.w-mean)*(v2.w-mean);
  #pragma unroll
  for (int off = 32; off > 0; off >>= 1) q += __shfl_xor(q, off);
  const float rs = rsqrtf(q * (1.0f / DM) + 1e-5f);
  bf16_t* o = out + (size_t)row * DM;
  #pragma unroll
  for (int i = 0; i < 3; ++i) {
    const int cc = c + i * 256;
    float4 vv = i == 0 ? v0 : (i == 1 ? v1 : v2);
    float4 ww = *(const float4*)&w[cc];
    float4 bb = *(const float4*)&b[cc];
    bf16x4 ob;
    ob[0] = (bf16_t)((vv.x - mean) * rs * ww.x + bb.x);
    ob[1] = (bf16_t)((vv.y - mean) * rs * ww.y + bb.y);
    ob[2] = (bf16_t)((vv.z - mean) * rs * ww.z + bb.z);
    ob[3] = (bf16_t)((vv.w - mean) * rs * ww.w + bb.w);
    *(bf16x4*)&o[cc] = ob;
  }
}

// =====================================================================
// 256x256 8-phase GEMM (T2 swizzle + T3/T4 counted-vmcnt + T5 setprio).
// B operand comes pre-swizzled+blocked: [t][nb][256][8ch] (see transpose_all),
// so B-STAGE source is linear. A staged from row-major with per-lane swizzled
// source. SPLITK>1: blockIdx.z covers k-range [z*Kdim, (z+1)*Kdim) of a row
// of stride Kstride; EPI2 accumulates via f32 atomic (bias from z==0 only).
// =====================================================================
#define OFF(S, MAT, H) (((((S)*2 + (MAT))*2) + (H)) * 8192)

#define STAGE(S, MAT, H, T) do {                                                \
    const int _r0 = tid >> 3, _r1 = _r0 + 64, _c = tid & 7;                     \
    if ((MAT) == 0) {                                                           \
      const bf16_t* _g0 = A + (size_t)(m0 + ((_r0 >> 6) << 7) + (H)*64 + (_r0 & 63)) * Kstride \
              + (T)*64 + ((_c ^ (_r0 & 7)) << 3);                               \
      const bf16_t* _g1 = A + (size_t)(m0 + ((_r1 >> 6) << 7) + (H)*64 + (_r1 & 63)) * Kstride \
              + (T)*64 + ((_c ^ (_r1 & 7)) << 3);                               \
      gload_lds16(_g0, &lds[OFF(S, 0, H) + (w << 9)]);                          \
      gload_lds16(_g1, &lds[OFF(S, 0, H) + 4096 + (w << 9)]);                   \
    } else {                                                                    \
      const int _gr0 = ((_r0 >> 5) << 6) + (H)*32 + (_r0 & 31);                 \
      const int _gr1 = ((_r1 >> 5) << 6) + (H)*32 + (_r1 & 31);                 \
      const bf16_t* _bb = BTB + (((size_t)(T) * nbN + nb) << 14);               \
      gload_lds16(_bb + (_gr0 << 6) + (_c << 3), &lds[OFF(S, 1, H) + (w << 9)]);        \
      gload_lds16(_bb + (_gr1 << 6) + (_c << 3), &lds[OFF(S, 1, H) + 4096 + (w << 9)]); \
    }                                                                           \
  } while (0)

#define RD_A(S, MH) do {                                                        \
    _Pragma("unroll") for (int _mf = 0; _mf < 4; ++_mf) {                       \
      const int _lr = wr * 64 + _mf * 16 + l15;                                 \
      const int _x = _lr & 7;                                                   \
      af[_mf][0] = *(const bf16x8*)&lds[OFF(S,0,MH) + _lr*64 + ((l4 ^ _x) << 3)];        \
      af[_mf][1] = *(const bf16x8*)&lds[OFF(S,0,MH) + _lr*64 + (((4+l4) ^ _x) << 3)];    \
    } } while (0)

#define RD_B(S, NH) do {                                                        \
    _Pragma("unroll") for (int _nf = 0; _nf < 2; ++_nf) {                       \
      const int _lr = wc * 32 + _nf * 16 + l15;                                 \
      const int _x = _lr & 7;                                                   \
      bfr[_nf][0] = *(const bf16x8*)&lds[OFF(S,1,NH) + _lr*64 + ((l4 ^ _x) << 3)];       \
      bfr[_nf][1] = *(const bf16x8*)&lds[OFF(S,1,NH) + _lr*64 + (((4+l4) ^ _x) << 3)];   \
    } } while (0)

#define MM(MH, NH) do {                                                         \
    __builtin_amdgcn_s_setprio(1);                                              \
    _Pragma("unroll") for (int _ks = 0; _ks < 2; ++_ks)                         \
      _Pragma("unroll") for (int _mf = 0; _mf < 4; ++_mf)                       \
        _Pragma("unroll") for (int _nf = 0; _nf < 2; ++_nf)                     \
          acc[(MH)*4+_mf][(NH)*2+_nf] = __builtin_amdgcn_mfma_f32_16x16x32_bf16(\
              af[_mf][_ks], bfr[_nf][_ks], acc[(MH)*4+_mf][(NH)*2+_nf], 0,0,0); \
    __builtin_amdgcn_s_setprio(0);                                              \
  } while (0)

#define BAR()   __builtin_amdgcn_s_barrier()
#define LGKM0() asm volatile("s_waitcnt lgkmcnt(0)" ::: "memory")
#define LGKM8() asm volatile("s_waitcnt lgkmcnt(8)" ::: "memory")
#define VM6()   asm volatile("s_waitcnt vmcnt(6)" ::: "memory")

// EPI: 0 = +bias -> bf16 ; 1 = +bias, exact GELU -> bf16 ; 2 = +bias, += f32 resid
template <int EPI, int SPLITK>
__global__ __launch_bounds__(512, 2) void gemm8(const bf16_t* __restrict__ A,
                                                const bf16_t* __restrict__ BTB,
                                                const float* __restrict__ bias,
                                                bf16_t* __restrict__ outb,
                                                float* __restrict__ resid,
                                                int Ndim, int Kdim, int Kstride, int nbN) {
  __shared__ bf16_t lds[65536];   // 128 KB
  const int tid = threadIdx.x, lane = tid & 63, w = tid >> 6;
  const int wr = w >> 2, wc = w & 3;
  const int l15 = lane & 15, l4 = lane >> 4;
  const int zz = (SPLITK > 1) ? blockIdx.z : 0;
  A += (size_t)zz * Kdim;                                   // k-offset within row
  BTB += ((size_t)zz * (Kdim >> 6) * nbN) << 14;            // k-tile offset in blocked layout
  const int nb = blockIdx.x;
  const int m0 = blockIdx.y * 256, n0 = blockIdx.x * 256;
  const int nT = Kdim >> 6, nIter = Kdim >> 7;

  f32x4 acc[8][4] = {};
  bf16x8 af[4][2], bfr[2][2];

  // prologue: slot0 = tile0 (4 half-tiles), slot1 = tile1 (3 of 4; B.h0 staged at ph0)
  STAGE(0, 0, 0, 0); STAGE(0, 1, 0, 0); STAGE(0, 0, 1, 0); STAGE(0, 1, 1, 0);
  asm volatile("s_waitcnt vmcnt(4)" ::: "memory");
  STAGE(1, 0, 0, 1); STAGE(1, 1, 1, 1); STAGE(1, 0, 1, 1);
  asm volatile("s_waitcnt vmcnt(6)" ::: "memory");
  BAR();

  for (int it = 0; it < nIter; ++it) {
    const int t1 = 2 * it + 1;
    int ts0 = 2 * it + 2; if (ts0 >= nT) ts0 -= nT;   // wrap: harmless re-stage
    int ts1 = 2 * it + 3; if (ts1 >= nT) ts1 -= nT;
    // ph0: quadrant (0,0) of slot0 tile
    RD_A(0, 0); RD_B(0, 0); STAGE(1, 1, 0, t1);
    LGKM8(); BAR(); LGKM0(); MM(0, 0); BAR();
    // ph1: (0,1)
    RD_B(0, 1); STAGE(0, 0, 0, ts0);
    BAR(); LGKM0(); MM(0, 1); BAR();
    // ph2: (1,1)
    RD_A(0, 1); STAGE(0, 1, 1, ts0);
    BAR(); LGKM0(); MM(1, 1); BAR();
    // ph3: (1,0) ; vmcnt(6) -> slot1 fully visible for ph4-7
    RD_B(0, 0); STAGE(0, 0, 1, ts0);
    BAR(); LGKM0(); MM(1, 0); VM6(); BAR();
    // ph4: quadrant (0,0) of slot1 tile
    RD_A(1, 0); RD_B(1, 0); STAGE(0, 1, 0, ts0);
    LGKM8(); BAR(); LGKM0(); MM(0, 0); BAR();
    // ph5: (0,1)
    RD_B(1, 1); STAGE(1, 0, 0, ts1);
    BAR(); LGKM0(); MM(0, 1); BAR();
    // ph6: (1,1)
    RD_A(1, 1); STAGE(1, 1, 1, ts1);
    BAR(); LGKM0(); MM(1, 1); BAR();
    // ph7: (1,0) ; vmcnt(6) -> slot0 fully visible for next ph0-3
    RD_B(1, 0); STAGE(1, 0, 1, ts1);
    BAR(); LGKM0(); MM(1, 0); VM6(); BAR();
  }

  // epilogue
  #pragma unroll
  for (int mf = 0; mf < 8; ++mf) {
    #pragma unroll
    for (int nf = 0; nf < 4; ++nf) {
      const int col = n0 + wc * 64 + nf * 16 + l15;
      const float bv = (SPLITK == 1 || zz == 0) ? bias[col] : 0.0f;
      #pragma unroll
      for (int r = 0; r < 4; ++r) {
        const int row = m0 + wr * 128 + mf * 16 + l4 * 4 + r;
        float v = acc[mf][nf][r] + bv;
        if (EPI == 1) v = 0.5f * v * (1.0f + erff(v * 0.70710678118654752f));
        if (EPI == 2) {
          const size_t idx2 = (size_t)row * Ndim + col;
          if (SPLITK > 1) unsafeAtomicAdd(&resid[idx2], v);
          else            resid[idx2] += v;
        } else {
          outb[(size_t)row * Ndim + col] = (bf16_t)v;
        }
      }
    }
  }
}

// ---------------- fused flash attention (unchanged) ----------------
__global__ __launch_bounds__(512) void attn_kernel(const bf16_t* __restrict__ qkv,
                                                   bf16_t* __restrict__ y) {
  const int qt = blockIdx.x, hh = blockIdx.y, bb = blockIdx.z;
  const int tid = threadIdx.x, lane = tid & 63, w = tid >> 6;
  const int l31 = lane & 31, hiL = lane >> 5;

  __shared__ bf16_t smem[18432];
  bf16_t* Kbuf = smem;
  bf16_t* Vbuf = smem + 8192;

  const bf16_t* kb = qkv + (size_t)(bb * TT) * D3 + DM + hh * 64;
  const bf16_t* vb = qkv + (size_t)(bb * TT) * D3 + 2 * DM + hh * 64;

  const bf16_t* qptr = qkv + (size_t)(bb * TT + qt * 256 + w * 32 + l31) * D3 + hh * 64 + hiL * 8;
  bf16x8 qreg[4];
  #pragma unroll
  for (int ks = 0; ks < 4; ++ks) {
    bf16x8 v = *(const bf16x8*)(qptr + ks * 16);
    #pragma unroll
    for (int j = 0; j < 8; ++j) qreg[ks][j] = (bf16_t)((float)v[j] * 0.125f);
  }

  const int sr = tid >> 3, sc = tid & 7;
  #define ATTN_STAGE(KT, BUF)                                                     \
    {                                                                             \
      gload_lds16(kb + (size_t)((KT) * 64 + sr) * D3 + ((sc ^ (sr & 7)) * 8),     \
                  Kbuf + (BUF) * 4096 + (w << 9));                                \
      bf16x8 tv;                                                                  \
      _Pragma("unroll")                                                           \
      for (int j = 0; j < 8; ++j) tv[j] = vb[(size_t)((KT) * 64 + w * 8 + j) * D3 + lane]; \
      *(bf16x8*)&Vbuf[(BUF) * 4096 + lane * 64 + ((w ^ (lane & 7)) << 3)] = tv;   \
    }

  ATTN_STAGE(0, 0);

  f32x16 o0 = 0.0f, o1 = 0.0f;
  float m = -INFINITY, l = 0.0f;

  for (int kt = 0; kt < 8; ++kt) {
    __syncthreads();
    if (kt < 7) ATTN_STAGE(kt + 1, (kt + 1) & 1);

    const bf16_t* Kb = Kbuf + (kt & 1) * 4096;
    const bf16_t* Vb = Vbuf + (kt & 1) * 4096;

    f32x16 st0 = 0.0f, st1 = 0.0f;
    #pragma unroll
    for (int ks = 0; ks < 4; ++ks) {
      const int ch = (ks * 2 + hiL) ^ (l31 & 7);
      bf16x8 kf0 = *(const bf16x8*)&Kb[l31 * 64 + ch * 8];
      bf16x8 kf1 = *(const bf16x8*)&Kb[(32 + l31) * 64 + ch * 8];
      st0 = __builtin_amdgcn_mfma_f32_32x32x16_bf16(kf0, qreg[ks], st0, 0, 0, 0);
      st1 = __builtin_amdgcn_mfma_f32_32x32x16_bf16(kf1, qreg[ks], st1, 0, 0, 0);
    }

    float tm = fmaxf(st0[0], st1[0]);
    #pragma unroll
    for (int i = 1; i < 16; ++i) tm = fmaxf(tm, fmaxf(st0[i], st1[i]));
    tm = fmaxf(tm, __shfl_xor(tm, 32));
    const float mnew = fmaxf(m, tm);
    const float al = __expf(m - mnew);
    #pragma unroll
    for (int i = 0; i < 16; ++i) st0[i] = __expf(st0[i] - mnew);
    #pragma unroll
    for (int i = 0; i < 16; ++i) st1[i] = __expf(st1[i] - mnew);
    float ps = 0.0f;
    #pragma unroll
    for (int i = 0; i < 16; ++i) ps += st0[i] + st1[i];
    ps += __shfl_xor(ps, 32);
    l = l * al + ps;
    m = mnew;
    #pragma unroll
    for (int i = 0; i < 16; ++i) { o0[i] *= al; o1[i] *= al; }

    #pragma unroll
    for (int g = 0; g < 2; ++g) {
      unsigned u0, u1, u2, u3, u4, u5, u6, u7;
      if (g == 0) {
        u0 = pkbf(st0[0], st0[1]);   u1 = pkbf(st0[2], st0[3]);
        u2 = pkbf(st0[4], st0[5]);   u3 = pkbf(st0[6], st0[7]);
        u4 = pkbf(st0[8], st0[9]);   u5 = pkbf(st0[10], st0[11]);
        u6 = pkbf(st0[12], st0[13]); u7 = pkbf(st0[14], st0[15]);
      } else {
        u0 = pkbf(st1[0], st1[1]);   u1 = pkbf(st1[2], st1[3]);
        u2 = pkbf(st1[4], st1[5]);   u3 = pkbf(st1[6], st1[7]);
        u4 = pkbf(st1[8], st1[9]);   u5 = pkbf(st1[10], st1[11]);
        u6 = pkbf(st1[12], st1[13]); u7 = pkbf(st1[14], st1[15]);
      }
      #pragma unroll
      for (int ks2 = 0; ks2 < 2; ++ks2) {
        const unsigned a0 = ks2 ? u4 : u0, a1 = ks2 ? u5 : u1;
        const unsigned a2 = ks2 ? u6 : u2, a3 = ks2 ? u7 : u3;
        const unsigned own0 = hiL ? a2 : a0, own1 = hiL ? a3 : a1;
        const unsigned snd0 = hiL ? a0 : a2, snd1 = hiL ? a1 : a3;
        const unsigned rcv0 = (unsigned)__shfl_xor((int)snd0, 32);
        const unsigned rcv1 = (unsigned)__shfl_xor((int)snd1, 32);
        u32x4 fw;
        fw[0] = hiL ? rcv0 : own0;
        fw[1] = hiL ? rcv1 : own1;
        fw[2] = hiL ? own0 : rcv0;
        fw[3] = hiL ? own1 : rcv1;
        const bf16x8 pa = __builtin_bit_cast(bf16x8, fw);
        const int chv = (g * 4 + ks2 * 2 + hiL) ^ (l31 & 7);
        bf16x8 vf0 = *(const bf16x8*)&Vb[l31 * 64 + chv * 8];
        bf16x8 vf1 = *(const bf16x8*)&Vb[(32 + l31) * 64 + chv * 8];
        o0 = __builtin_amdgcn_mfma_f32_32x32x16_bf16(vf0, pa, o0, 0, 0, 0);
        o1 = __builtin_amdgcn_mfma_f32_32x32x16_bf16(vf1, pa, o1, 0, 0, 0);
      }
    }
  }

  __syncthreads();
  const float rl = 1.0f / l;
  bf16_t* Ob = smem;
  #pragma unroll
  for (int reg = 0; reg < 16; ++reg) {
    const int drow = (reg & 3) + 8 * (reg >> 2) + 4 * hiL;
    Ob[(w * 32 + l31) * 72 + drow]      = (bf16_t)(o0[reg] * rl);
    Ob[(w * 32 + l31) * 72 + 32 + drow] = (bf16_t)(o1[reg] * rl);
  }
  __syncthreads();
  const int qrow = tid >> 1, half = tid & 1;
  bf16_t* yp = y + (size_t)(bb * TT + qt * 256 + qrow) * DM + hh * 64 + half * 32;
  const bf16_t* obp = &Ob[qrow * 72 + half * 32];
  *(bf16x8*)(yp)      = *(const bf16x8*)(obp);
  *(bf16x8*)(yp + 8)  = *(const bf16x8*)(obp + 8);
  *(bf16x8*)(yp + 16) = *(const bf16x8*)(obp + 16);
  *(bf16x8*)(yp + 24) = *(const bf16x8*)(obp + 24);
  #undef ATTN_STAGE
}

// ---------------- final LN (CLS) + dense + tanh -> pooled ----------------
__global__ __launch_bounds__(256) void pooled_kernel(const float* __restrict__ x,
                                                     const float* __restrict__ lnw,
                                                     const float* __restrict__ lnb,
                                                     const float* __restrict__ dw,
                                                     const float* __restrict__ db,
                                                     float* __restrict__ pooled) {
  const int bb = blockIdx.y, tid = threadIdx.x;
  const int lane = tid & 63, wv = tid >> 6;
  const float* xr = x + (size_t)(bb * TT) * DM;
  float v0 = xr[tid], v1 = xr[tid + 256], v2 = xr[tid + 512];
  __shared__ float red[8];
  __shared__ float lx[DM];
  float s = v0 + v1 + v2;
  #pragma unroll
  for (int off = 32; off > 0; off >>= 1) s += __shfl_down(s, off);
  if (lane == 0) red[wv] = s;
  __syncthreads();
  const float mean = (red[0] + red[1] + red[2] + red[3]) * (1.0f / DM);
  const float d0 = v0 - mean, d1 = v1 - mean, d2 = v2 - mean;
  float q = d0 * d0 + d1 * d1 + d2 * d2;
  #pragma unroll
  for (int off = 32; off > 0; off >>= 1) q += __shfl_down(q, off);
  __syncthreads();
  if (lane == 0) red[wv] = q;
  __syncthreads();
  const float var = (red[0] + red[1] + red[2] + red[3]) * (1.0f / DM);
  const float rs = rsqrtf(var + 1e-5f);

  lx[tid]       = d0 * rs * lnw[tid] + lnb[tid];
  lx[tid + 256] = d1 * rs * lnw[tid + 256] + lnb[tid + 256];
  lx[tid + 512] = d2 * rs * lnw[tid + 512] + lnb[tid + 512];
  __syncthreads();

  const int j = blockIdx.x * 64 + (tid >> 2), sl = tid & 3;
  const int k0 = sl * 192;
  float acc = 0.0f;
  #pragma unroll 4
  for (int k = k0; k < k0 + 192; ++k) acc += lx[k] * dw[(size_t)k * DM + j];
  acc += __shfl_xor(acc, 1);
  acc += __shfl_xor(acc, 2);
  if (sl == 0) pooled[bb * DM + j] = tanhf(acc + db[j]);
}

// ---------------- logits ----------------
__global__ void logits_kernel(const float* __restrict__ pooled,
                              const float* __restrict__ hw,
                              const float* __restrict__ hb,
                              float* __restrict__ out) {
  const int tid = threadIdx.x;
  if (tid < 32) {
    const int bb = tid >> 1, c = tid & 1;
    float acc = hb[c];
    for (int k = 0; k < DM; ++k) acc += pooled[bb * DM + k] * hw[k * 2 + c];
    out[bb * 2 + c] = acc;
  }
}

extern "C" void kernel_launch(void* const* d_in, const int* in_sizes, int n_in,
                              void* d_out, int out_size, void* d_ws, size_t ws_size,
                              hipStream_t stream) {
  const int*   ids   = (const int*)d_in[0];
  const float* wte   = (const float*)d_in[3];
  const float* wpe   = (const float*)d_in[4];
  const float* ln1w  = (const float*)d_in[5];
  const float* ln1b  = (const float*)d_in[6];
  const float* wqkv  = (const float*)d_in[7];
  const float* bqkv  = (const float*)d_in[8];
  const float* wo    = (const float*)d_in[9];
  const float* bo    = (const float*)d_in[10];
  const float* ln2w  = (const float*)d_in[11];
  const float* ln2b  = (const float*)d_in[12];
  const float* wfc   = (const float*)d_in[13];
  const float* bfc   = (const float*)d_in[14];
  const float* wproj = (const float*)d_in[15];
  const float* bproj = (const float*)d_in[16];
  const float* lnfw  = (const float*)d_in[17];
  const float* lnfb  = (const float*)d_in[18];
  const float* dw    = (const float*)d_in[19];
  const float* db    = (const float*)d_in[20];
  const float* hw    = (const float*)d_in[21];
  const float* hb    = (const float*)d_in[22];
  float* out = (float*)d_out;

  const size_t NEED_FULL = 308330496ULL;
  const bool full = ws_size >= NEED_FULL;

  char* ws = (char*)d_ws;
  size_t off = 0;
  auto alloc = [&](size_t bytes) -> void* {
    void* p = ws + off;
    off += (bytes + 255) & ~(size_t)255;
    return p;
  };
  float*  x      = (float*)alloc((size_t)MR * DM * 4);
  bf16_t* h      = (bf16_t*)alloc((size_t)MR * DM * 2);
  bf16_t* qkvb   = (bf16_t*)alloc((size_t)MR * D3 * 2);
  bf16_t* yb     = (bf16_t*)alloc((size_t)MR * DM * 2);
  bf16_t* ub     = (bf16_t*)alloc((size_t)MR * D4 * 2);
  float*  pooled = (float*)alloc((size_t)NB * DM * 4);
  const size_t wmul = full ? NL : 1;
  bf16_t* wqkvT  = (bf16_t*)alloc((size_t)D3 * DM * 2 * wmul);
  bf16_t* woT    = (bf16_t*)alloc((size_t)DM * DM * 2 * wmul);
  bf16_t* wfcT   = (bf16_t*)alloc((size_t)D4 * DM * 2 * wmul);
  bf16_t* wprojT = (bf16_t*)alloc((size_t)DM * D4 * 2 * wmul);

  embed_kernel<<<MR, 256, 0, stream>>>(ids, wte, wpe, x);

  if (full) {
    transpose_all<<<dim3(1728, 1, NL), 256, 0, stream>>>(
        wqkv, wo, wfc, wproj, wqkvT, woT, wfcT, wprojT, 0, 0);
  }

  for (int l = 0; l < NL; ++l) {
    if (!full) {
      transpose_all<<<dim3(1728, 1, 1), 256, 0, stream>>>(
          wqkv, wo, wfc, wproj, wqkvT, woT, wfcT, wprojT, l, 1);
    }
    bf16_t* qkvT_l = wqkvT + (full ? (size_t)l * D3 * DM : 0);
    bf16_t* woT_l  = woT   + (full ? (size_t)l * DM * DM : 0);
    bf16_t* fcT_l  = wfcT  + (full ? (size_t)l * D4 * DM : 0);
    bf16_t* prT_l  = wprojT+ (full ? (size_t)l * DM * D4 : 0);

    ln_kernel<<<MR / 4, 256, 0, stream>>>(x, ln1w + l * DM, ln1b + l * DM, h);
    gemm8<0, 1><<<dim3(D3 / 256, MR / 256, 1), 512, 0, stream>>>(
        h, qkvT_l, bqkv + (size_t)l * D3, qkvb, nullptr, D3, DM, DM, D3 / 256);
    attn_kernel<<<dim3(TT / 256, NH, NB), 512, 0, stream>>>(qkvb, yb);
    gemm8<2, 2><<<dim3(DM / 256, MR / 256, 2), 512, 0, stream>>>(
        yb, woT_l, bo + (size_t)l * DM, nullptr, x, DM, DM / 2, DM, DM / 256);
    ln_kernel<<<MR / 4, 256, 0, stream>>>(x, ln2w + l * DM, ln2b + l * DM, h);
    gemm8<1, 1><<<dim3(D4 / 256, MR / 256, 1), 512, 0, stream>>>(
        h, fcT_l, bfc + (size_t)l * D4, ub, nullptr, D4, DM, DM, D4 / 256);
    gemm8<2, 2><<<dim3(DM / 256, MR / 256, 2), 512, 0, stream>>>(
        ub, prT_l, bproj + (size_t)l * DM, nullptr, x, DM, D4 / 2, D4, DM / 256);
  }

  pooled_kernel<<<dim3(12, NB), 256, 0, stream>>>(x, lnfw, lnfb, dw, db, pooled);
  logits_kernel<<<1, 64, 0, stream>>>(pooled, hw, hb, out);
}

// Round 6
// 3699.014 us; speedup vs baseline: 1.1263x; 1.0528x over previous
//
#include <hip/hip_runtime.h>
#include <hip/hip_bf16.h>
#include <math.h>

// Problem constants
#define NL 12
#define NH 12
#define DM 768
#define DH 64
#define TT 512
#define NB 16
#define MR (NB*TT)      // 8192 rows
#define D3 (3*DM)       // 2304
#define D4 (4*DM)       // 3072

typedef __bf16 bf16_t;
typedef __attribute__((ext_vector_type(8))) __bf16 bf16x8;
typedef __attribute__((ext_vector_type(4))) __bf16 bf16x4;
typedef __attribute__((ext_vector_type(4))) float f32x4;
typedef __attribute__((ext_vector_type(16))) float f32x16;
typedef __attribute__((ext_vector_type(4))) unsigned int u32x4;

// ---- async global->LDS, 16B per lane. LDS dst is wave-uniform base; HW writes
// lane i at base + i*16. Global src is per-lane. ----
__device__ __forceinline__ void gload_lds16(const void* g, void* l) {
  __builtin_amdgcn_global_load_lds(
      (const __attribute__((address_space(1))) unsigned int*)g,
      (__attribute__((address_space(3))) unsigned int*)l,
      16, 0, 0);
}

__device__ __forceinline__ unsigned pkbf(float a, float b) {
  unsigned short ua = __builtin_bit_cast(unsigned short, (bf16_t)a);
  unsigned short ub = __builtin_bit_cast(unsigned short, (bf16_t)b);
  return (unsigned)ua | ((unsigned)ub << 16);
}

// ---------------- batched weight transpose + f32->bf16 into BLOCKED layout ----------------
// 256n x 64k tiles. Output: [ktile t][nb][row r 0..255][chunk c 0..7][8 bf16];
// stored chunk c holds original k-chunk (c ^ (r&7)) -- the pre-swizzled image
// gemm8's B-STAGE wants (linear source, XOR read).
// Regions (tiles/layer): qkv 9x12=108 | wo 3x12=36 (->144) | fc 12x12=144 (->288) | proj 3x48=144 (->432)
__global__ __launch_bounds__(256) void transpose_all(
    const float* __restrict__ wqkv, const float* __restrict__ wo,
    const float* __restrict__ wfc, const float* __restrict__ wproj,
    bf16_t* __restrict__ qkvT, bf16_t* __restrict__ woT,
    bf16_t* __restrict__ fcT, bf16_t* __restrict__ projT,
    int l0, int per_layer_out) {
  const int lay = l0 + blockIdx.z;
  int bid = blockIdx.x;
  const float* in; bf16_t* out; int K, N;
  if (bid < 108) {
    in = wqkv + (size_t)lay * DM * D3;
    out = qkvT + (per_layer_out ? 0 : (size_t)lay * D3 * DM);
    K = DM; N = D3;
  } else if (bid < 144) {
    bid -= 108;
    in = wo + (size_t)lay * DM * DM;
    out = woT + (per_layer_out ? 0 : (size_t)lay * DM * DM);
    K = DM; N = DM;
  } else if (bid < 288) {
    bid -= 144;
    in = wfc + (size_t)lay * DM * D4;
    out = fcT + (per_layer_out ? 0 : (size_t)lay * D4 * DM);
    K = DM; N = D4;
  } else {
    bid -= 288;
    in = wproj + (size_t)lay * D4 * DM;
    out = projT + (per_layer_out ? 0 : (size_t)lay * DM * D4);
    K = D4; N = DM;
  }
  const int nx = N >> 8;
  const int n0 = (bid % nx) * 256, k0 = (bid / nx) * 64;
  __shared__ float tile[64][256];   // 64 KB -> 2 blocks/CU
  const int t = threadIdx.x;
  const int cc4 = (t & 63) * 4, rr = t >> 6;
  #pragma unroll
  for (int it = 0; it < 16; ++it) {
    const int row = rr + it * 4;
    *(float4*)&tile[row][cc4] = *(const float4*)&in[(size_t)(k0 + row) * N + n0 + cc4];
  }
  __syncthreads();
  // thread t owns output row r = t (64 k values = 8 chunks), XOR-placed.
  const int nbN = N >> 8;
  const int nb = n0 >> 8;
  const int x = t & 7;
  bf16_t* base = out + (((size_t)(k0 >> 6) * nbN + nb) * 256 + t) * 64;
  #pragma unroll
  for (int p = 0; p < 8; ++p) {
    const int s = p ^ x;                // original chunk stored at position p
    bf16x8 o;
    #pragma unroll
    for (int j = 0; j < 8; ++j) o[j] = (bf16_t)tile[s * 8 + j][t];
    *(bf16x8*)(base + (p << 3)) = o;
  }
}

// ---------------- embedding ----------------
__global__ __launch_bounds__(256) void embed_kernel(const int* __restrict__ ids,
                                                    const float* __restrict__ wte,
                                                    const float* __restrict__ wpe,
                                                    float* __restrict__ x) {
  const int row = blockIdx.x;
  const int t = row & (TT - 1);
  const int id = ids[row];
  const int tid = threadIdx.x;
  #pragma unroll
  for (int i = 0; i < 3; ++i) {
    const int c = tid + i * 256;
    x[(size_t)row * DM + c] = wte[(size_t)id * DM + c] + wpe[(size_t)t * DM + c];
  }
}

// ---------------- LayerNorm (f32 in -> bf16 out), one WAVE per row ----------------
__global__ __launch_bounds__(256) void ln_kernel(const float* __restrict__ x,
                                                 const float* __restrict__ w,
                                                 const float* __restrict__ b,
                                                 bf16_t* __restrict__ out) {
  const int lane = threadIdx.x & 63, wv = threadIdx.x >> 6;
  const int row = blockIdx.x * 4 + wv;
  const float* xr = x + (size_t)row * DM;
  const int c = lane * 4;
  float4 v0 = *(const float4*)&xr[c];
  float4 v1 = *(const float4*)&xr[c + 256];
  float4 v2 = *(const float4*)&xr[c + 512];
  float s = v0.x + v0.y + v0.z + v0.w + v1.x + v1.y + v1.z + v1.w
          + v2.x + v2.y + v2.z + v2.w;
  #pragma unroll
  for (int off = 32; off > 0; off >>= 1) s += __shfl_xor(s, off);
  const float mean = s * (1.0f / DM);
  float q = 0.0f;
  q += (v0.x-mean)*(v0.x-mean) + (v0.y-mean)*(v0.y-mean) + (v0.z-mean)*(v0.z-mean) + (v0.w-mean)*(v0.w-mean);
  q += (v1.x-mean)*(v1.x-mean) + (v1.y-mean)*(v1.y-mean) + (v1.z-mean)*(v1.z-mean) + (v1.w-mean)*(v1.w-mean);
  q += (v2.x-mean)*(v2.x-mean) + (v2.y-mean)*(v2.y-mean) + (v2.z-mean)*(v2.z-mean) + (v2.w-mean)*(v2.w-mean);
  #pragma unroll
  for (int off = 32; off > 0; off >>= 1) q += __shfl_xor(q, off);
  const float rs = rsqrtf(q * (1.0f / DM) + 1e-5f);
  bf16_t* o = out + (size_t)row * DM;
  #pragma unroll
  for (int i = 0; i < 3; ++i) {
    const int cc = c + i * 256;
    float4 vv = i == 0 ? v0 : (i == 1 ? v1 : v2);
    float4 ww = *(const float4*)&w[cc];
    float4 bb = *(const float4*)&b[cc];
    bf16x4 ob;
    ob[0] = (bf16_t)((vv.x - mean) * rs * ww.x + bb.x);
    ob[1] = (bf16_t)((vv.y - mean) * rs * ww.y + bb.y);
    ob[2] = (bf16_t)((vv.z - mean) * rs * ww.z + bb.z);
    ob[3] = (bf16_t)((vv.w - mean) * rs * ww.w + bb.w);
    *(bf16x4*)&o[cc] = ob;
  }
}

// =====================================================================
// 256x256 8-phase GEMM (T1 XCD swizzle + T2 swizzle + T3/T4 counted-vmcnt
// + T5 setprio). B operand pre-swizzled+blocked [t][nb][256][8ch].
// SPLITK>1: blockIdx.z covers k-range; EPI2 accumulates via f32 atomic.
// =====================================================================
#define OFF(S, MAT, H) (((((S)*2 + (MAT))*2) + (H)) * 8192)

#define STAGE(S, MAT, H, T) do {                                                \
    const int _r0 = tid >> 3, _r1 = _r0 + 64, _c = tid & 7;                     \
    if ((MAT) == 0) {                                                           \
      const bf16_t* _g0 = A + (size_t)(m0 + ((_r0 >> 6) << 7) + (H)*64 + (_r0 & 63)) * Kstride \
              + (T)*64 + ((_c ^ (_r0 & 7)) << 3);                               \
      const bf16_t* _g1 = A + (size_t)(m0 + ((_r1 >> 6) << 7) + (H)*64 + (_r1 & 63)) * Kstride \
              + (T)*64 + ((_c ^ (_r1 & 7)) << 3);                               \
      gload_lds16(_g0, &lds[OFF(S, 0, H) + (w << 9)]);                          \
      gload_lds16(_g1, &lds[OFF(S, 0, H) + 4096 + (w << 9)]);                   \
    } else {                                                                    \
      const int _gr0 = ((_r0 >> 5) << 6) + (H)*32 + (_r0 & 31);                 \
      const int _gr1 = ((_r1 >> 5) << 6) + (H)*32 + (_r1 & 31);                 \
      const bf16_t* _bb = BTB + (((size_t)(T) * nbN + nb) << 14);               \
      gload_lds16(_bb + (_gr0 << 6) + (_c << 3), &lds[OFF(S, 1, H) + (w << 9)]);        \
      gload_lds16(_bb + (_gr1 << 6) + (_c << 3), &lds[OFF(S, 1, H) + 4096 + (w << 9)]); \
    }                                                                           \
  } while (0)

#define RD_A(S, MH) do {                                                        \
    _Pragma("unroll") for (int _mf = 0; _mf < 4; ++_mf) {                       \
      const int _lr = wr * 64 + _mf * 16 + l15;                                 \
      const int _x = _lr & 7;                                                   \
      af[_mf][0] = *(const bf16x8*)&lds[OFF(S,0,MH) + _lr*64 + ((l4 ^ _x) << 3)];        \
      af[_mf][1] = *(const bf16x8*)&lds[OFF(S,0,MH) + _lr*64 + (((4+l4) ^ _x) << 3)];    \
    } } while (0)

#define RD_B(S, NH) do {                                                        \
    _Pragma("unroll") for (int _nf = 0; _nf < 2; ++_nf) {                       \
      const int _lr = wc * 32 + _nf * 16 + l15;                                 \
      const int _x = _lr & 7;                                                   \
      bfr[_nf][0] = *(const bf16x8*)&lds[OFF(S,1,NH) + _lr*64 + ((l4 ^ _x) << 3)];       \
      bfr[_nf][1] = *(const bf16x8*)&lds[OFF(S,1,NH) + _lr*64 + (((4+l4) ^ _x) << 3)];   \
    } } while (0)

#define MM(MH, NH) do {                                                         \
    __builtin_amdgcn_s_setprio(1);                                              \
    _Pragma("unroll") for (int _ks = 0; _ks < 2; ++_ks)                         \
      _Pragma("unroll") for (int _mf = 0; _mf < 4; ++_mf)                       \
        _Pragma("unroll") for (int _nf = 0; _nf < 2; ++_nf)                     \
          acc[(MH)*4+_mf][(NH)*2+_nf] = __builtin_amdgcn_mfma_f32_16x16x32_bf16(\
              af[_mf][_ks], bfr[_nf][_ks], acc[(MH)*4+_mf][(NH)*2+_nf], 0,0,0); \
    __builtin_amdgcn_s_setprio(0);                                              \
  } while (0)

#define BAR()   __builtin_amdgcn_s_barrier()
#define LGKM0() asm volatile("s_waitcnt lgkmcnt(0)" ::: "memory")
#define LGKM8() asm volatile("s_waitcnt lgkmcnt(8)" ::: "memory")
#define VM6()   asm volatile("s_waitcnt vmcnt(6)" ::: "memory")

// EPI: 0 = +bias -> bf16 ; 1 = +bias, tanh-approx GELU -> bf16 ; 2 = +bias, += f32 resid
template <int EPI, int SPLITK>
__global__ __launch_bounds__(512, 2) void gemm8(const bf16_t* __restrict__ A,
                                                const bf16_t* __restrict__ BTB,
                                                const float* __restrict__ bias,
                                                bf16_t* __restrict__ outb,
                                                float* __restrict__ resid,
                                                int Ndim, int Kdim, int Kstride, int nbN) {
  __shared__ bf16_t lds[65536];   // 128 KB
  const int tid = threadIdx.x, lane = tid & 63, w = tid >> 6;
  const int wr = w >> 2, wc = w & 3;
  const int l15 = lane & 15, l4 = lane >> 4;
  const int zz = (SPLITK > 1) ? blockIdx.z : 0;
  A += (size_t)zz * Kdim;
  BTB += ((size_t)zz * (Kdim >> 6) * nbN) << 14;

  // T1: bijective XCD-aware tile swizzle (m204). All grids here are %8==0 (r8=0).
  const unsigned nwg = gridDim.x * gridDim.y;
  const unsigned orig = blockIdx.y * gridDim.x + blockIdx.x;
  const unsigned q8 = nwg >> 3;
  const unsigned wg = (orig & 7) * q8 + (orig >> 3);
  const int nb = (int)(wg % gridDim.x);
  const int m0 = (int)(wg / gridDim.x) * 256, n0 = nb * 256;
  const int nT = Kdim >> 6, nIter = Kdim >> 7;

  f32x4 acc[8][4] = {};
  bf16x8 af[4][2], bfr[2][2];

  // prologue: slot0 = tile0 (4 half-tiles), slot1 = tile1 (3 of 4; B.h0 staged at ph0)
  STAGE(0, 0, 0, 0); STAGE(0, 1, 0, 0); STAGE(0, 0, 1, 0); STAGE(0, 1, 1, 0);
  asm volatile("s_waitcnt vmcnt(4)" ::: "memory");
  STAGE(1, 0, 0, 1); STAGE(1, 1, 1, 1); STAGE(1, 0, 1, 1);
  asm volatile("s_waitcnt vmcnt(6)" ::: "memory");
  BAR();

  for (int it = 0; it < nIter; ++it) {
    const int t1 = 2 * it + 1;
    int ts0 = 2 * it + 2; if (ts0 >= nT) ts0 -= nT;   // wrap: harmless re-stage
    int ts1 = 2 * it + 3; if (ts1 >= nT) ts1 -= nT;
    // ph0
    RD_A(0, 0); RD_B(0, 0); STAGE(1, 1, 0, t1);
    LGKM8(); BAR(); LGKM0(); MM(0, 0); BAR();
    // ph1
    RD_B(0, 1); STAGE(0, 0, 0, ts0);
    BAR(); LGKM0(); MM(0, 1); BAR();
    // ph2
    RD_A(0, 1); STAGE(0, 1, 1, ts0);
    BAR(); LGKM0(); MM(1, 1); BAR();
    // ph3 ; vmcnt(6) -> slot1 fully visible for ph4-7
    RD_B(0, 0); STAGE(0, 0, 1, ts0);
    BAR(); LGKM0(); MM(1, 0); VM6(); BAR();
    // ph4
    RD_A(1, 0); RD_B(1, 0); STAGE(0, 1, 0, ts0);
    LGKM8(); BAR(); LGKM0(); MM(0, 0); BAR();
    // ph5
    RD_B(1, 1); STAGE(1, 0, 0, ts1);
    BAR(); LGKM0(); MM(0, 1); BAR();
    // ph6
    RD_A(1, 1); STAGE(1, 1, 1, ts1);
    BAR(); LGKM0(); MM(1, 1); BAR();
    // ph7 ; vmcnt(6) -> slot0 fully visible for next ph0-3
    RD_B(1, 0); STAGE(1, 0, 1, ts1);
    BAR(); LGKM0(); MM(1, 0); VM6(); BAR();
  }

  // epilogue
  #pragma unroll
  for (int mf = 0; mf < 8; ++mf) {
    #pragma unroll
    for (int nf = 0; nf < 4; ++nf) {
      const int col = n0 + wc * 64 + nf * 16 + l15;
      const float bv = (SPLITK == 1 || zz == 0) ? bias[col] : 0.0f;
      #pragma unroll
      for (int r = 0; r < 4; ++r) {
        const int row = m0 + wr * 128 + mf * 16 + l4 * 4 + r;
        float v = acc[mf][nf][r] + bv;
        if (EPI == 1) {
          // tanh-approx GELU in sigmoid form: u*sigmoid(1.59577(u+0.044715u^3))
          const float z2 = 1.5957692f * v + 0.07135481f * v * v * v;
          v = v / (1.0f + __expf(-z2));
        }
        if (EPI == 2) {
          const size_t idx2 = (size_t)row * Ndim + col;
          if (SPLITK > 1) unsafeAtomicAdd(&resid[idx2], v);
          else            resid[idx2] += v;
        } else {
          outb[(size_t)row * Ndim + col] = (bf16_t)v;
        }
      }
    }
  }
}

// ---------------- fused flash attention (unchanged) ----------------
__global__ __launch_bounds__(512) void attn_kernel(const bf16_t* __restrict__ qkv,
                                                   bf16_t* __restrict__ y) {
  const int qt = blockIdx.x, hh = blockIdx.y, bb = blockIdx.z;
  const int tid = threadIdx.x, lane = tid & 63, w = tid >> 6;
  const int l31 = lane & 31, hiL = lane >> 5;

  __shared__ bf16_t smem[18432];
  bf16_t* Kbuf = smem;
  bf16_t* Vbuf = smem + 8192;

  const bf16_t* kb = qkv + (size_t)(bb * TT) * D3 + DM + hh * 64;
  const bf16_t* vb = qkv + (size_t)(bb * TT) * D3 + 2 * DM + hh * 64;

  const bf16_t* qptr = qkv + (size_t)(bb * TT + qt * 256 + w * 32 + l31) * D3 + hh * 64 + hiL * 8;
  bf16x8 qreg[4];
  #pragma unroll
  for (int ks = 0; ks < 4; ++ks) {
    bf16x8 v = *(const bf16x8*)(qptr + ks * 16);
    #pragma unroll
    for (int j = 0; j < 8; ++j) qreg[ks][j] = (bf16_t)((float)v[j] * 0.125f);
  }

  const int sr = tid >> 3, sc = tid & 7;
  #define ATTN_STAGE(KT, BUF)                                                     \
    {                                                                             \
      gload_lds16(kb + (size_t)((KT) * 64 + sr) * D3 + ((sc ^ (sr & 7)) * 8),     \
                  Kbuf + (BUF) * 4096 + (w << 9));                                \
      bf16x8 tv;                                                                  \
      _Pragma("unroll")                                                           \
      for (int j = 0; j < 8; ++j) tv[j] = vb[(size_t)((KT) * 64 + w * 8 + j) * D3 + lane]; \
      *(bf16x8*)&Vbuf[(BUF) * 4096 + lane * 64 + ((w ^ (lane & 7)) << 3)] = tv;   \
    }

  ATTN_STAGE(0, 0);

  f32x16 o0 = 0.0f, o1 = 0.0f;
  float m = -INFINITY, l = 0.0f;

  for (int kt = 0; kt < 8; ++kt) {
    __syncthreads();
    if (kt < 7) ATTN_STAGE(kt + 1, (kt + 1) & 1);

    const bf16_t* Kb = Kbuf + (kt & 1) * 4096;
    const bf16_t* Vb = Vbuf + (kt & 1) * 4096;

    f32x16 st0 = 0.0f, st1 = 0.0f;
    #pragma unroll
    for (int ks = 0; ks < 4; ++ks) {
      const int ch = (ks * 2 + hiL) ^ (l31 & 7);
      bf16x8 kf0 = *(const bf16x8*)&Kb[l31 * 64 + ch * 8];
      bf16x8 kf1 = *(const bf16x8*)&Kb[(32 + l31) * 64 + ch * 8];
      st0 = __builtin_amdgcn_mfma_f32_32x32x16_bf16(kf0, qreg[ks], st0, 0, 0, 0);
      st1 = __builtin_amdgcn_mfma_f32_32x32x16_bf16(kf1, qreg[ks], st1, 0, 0, 0);
    }

    float tm = fmaxf(st0[0], st1[0]);
    #pragma unroll
    for (int i = 1; i < 16; ++i) tm = fmaxf(tm, fmaxf(st0[i], st1[i]));
    tm = fmaxf(tm, __shfl_xor(tm, 32));
    const float mnew = fmaxf(m, tm);
    const float al = __expf(m - mnew);
    #pragma unroll
    for (int i = 0; i < 16; ++i) st0[i] = __expf(st0[i] - mnew);
    #pragma unroll
    for (int i = 0; i < 16; ++i) st1[i] = __expf(st1[i] - mnew);
    float ps = 0.0f;
    #pragma unroll
    for (int i = 0; i < 16; ++i) ps += st0[i] + st1[i];
    ps += __shfl_xor(ps, 32);
    l = l * al + ps;
    m = mnew;
    #pragma unroll
    for (int i = 0; i < 16; ++i) { o0[i] *= al; o1[i] *= al; }

    #pragma unroll
    for (int g = 0; g < 2; ++g) {
      unsigned u0, u1, u2, u3, u4, u5, u6, u7;
      if (g == 0) {
        u0 = pkbf(st0[0], st0[1]);   u1 = pkbf(st0[2], st0[3]);
        u2 = pkbf(st0[4], st0[5]);   u3 = pkbf(st0[6], st0[7]);
        u4 = pkbf(st0[8], st0[9]);   u5 = pkbf(st0[10], st0[11]);
        u6 = pkbf(st0[12], st0[13]); u7 = pkbf(st0[14], st0[15]);
      } else {
        u0 = pkbf(st1[0], st1[1]);   u1 = pkbf(st1[2], st1[3]);
        u2 = pkbf(st1[4], st1[5]);   u3 = pkbf(st1[6], st1[7]);
        u4 = pkbf(st1[8], st1[9]);   u5 = pkbf(st1[10], st1[11]);
        u6 = pkbf(st1[12], st1[13]); u7 = pkbf(st1[14], st1[15]);
      }
      #pragma unroll
      for (int ks2 = 0; ks2 < 2; ++ks2) {
        const unsigned a0 = ks2 ? u4 : u0, a1 = ks2 ? u5 : u1;
        const unsigned a2 = ks2 ? u6 : u2, a3 = ks2 ? u7 : u3;
        const unsigned own0 = hiL ? a2 : a0, own1 = hiL ? a3 : a1;
        const unsigned snd0 = hiL ? a0 : a2, snd1 = hiL ? a1 : a3;
        const unsigned rcv0 = (unsigned)__shfl_xor((int)snd0, 32);
        const unsigned rcv1 = (unsigned)__shfl_xor((int)snd1, 32);
        u32x4 fw;
        fw[0] = hiL ? rcv0 : own0;
        fw[1] = hiL ? rcv1 : own1;
        fw[2] = hiL ? own0 : rcv0;
        fw[3] = hiL ? own1 : rcv1;
        const bf16x8 pa = __builtin_bit_cast(bf16x8, fw);
        const int chv = (g * 4 + ks2 * 2 + hiL) ^ (l31 & 7);
        bf16x8 vf0 = *(const bf16x8*)&Vb[l31 * 64 + chv * 8];
        bf16x8 vf1 = *(const bf16x8*)&Vb[(32 + l31) * 64 + chv * 8];
        o0 = __builtin_amdgcn_mfma_f32_32x32x16_bf16(vf0, pa, o0, 0, 0, 0);
        o1 = __builtin_amdgcn_mfma_f32_32x32x16_bf16(vf1, pa, o1, 0, 0, 0);
      }
    }
  }

  __syncthreads();
  const float rl = 1.0f / l;
  bf16_t* Ob = smem;
  #pragma unroll
  for (int reg = 0; reg < 16; ++reg) {
    const int drow = (reg & 3) + 8 * (reg >> 2) + 4 * hiL;
    Ob[(w * 32 + l31) * 72 + drow]      = (bf16_t)(o0[reg] * rl);
    Ob[(w * 32 + l31) * 72 + 32 + drow] = (bf16_t)(o1[reg] * rl);
  }
  __syncthreads();
  const int qrow = tid >> 1, half = tid & 1;
  bf16_t* yp = y + (size_t)(bb * TT + qt * 256 + qrow) * DM + hh * 64 + half * 32;
  const bf16_t* obp = &Ob[qrow * 72 + half * 32];
  *(bf16x8*)(yp)      = *(const bf16x8*)(obp);
  *(bf16x8*)(yp + 8)  = *(const bf16x8*)(obp + 8);
  *(bf16x8*)(yp + 16) = *(const bf16x8*)(obp + 16);
  *(bf16x8*)(yp + 24) = *(const bf16x8*)(obp + 24);
  #undef ATTN_STAGE
}

// ---------------- final LN (CLS) + dense + tanh -> pooled ----------------
__global__ __launch_bounds__(256) void pooled_kernel(const float* __restrict__ x,
                                                     const float* __restrict__ lnw,
                                                     const float* __restrict__ lnb,
                                                     const float* __restrict__ dw,
                                                     const float* __restrict__ db,
                                                     float* __restrict__ pooled) {
  const int bb = blockIdx.y, tid = threadIdx.x;
  const int lane = tid & 63, wv = tid >> 6;
  const float* xr = x + (size_t)(bb * TT) * DM;
  float v0 = xr[tid], v1 = xr[tid + 256], v2 = xr[tid + 512];
  __shared__ float red[8];
  __shared__ float lx[DM];
  float s = v0 + v1 + v2;
  #pragma unroll
  for (int off = 32; off > 0; off >>= 1) s += __shfl_down(s, off);
  if (lane == 0) red[wv] = s;
  __syncthreads();
  const float mean = (red[0] + red[1] + red[2] + red[3]) * (1.0f / DM);
  const float d0 = v0 - mean, d1 = v1 - mean, d2 = v2 - mean;
  float q = d0 * d0 + d1 * d1 + d2 * d2;
  #pragma unroll
  for (int off = 32; off > 0; off >>= 1) q += __shfl_down(q, off);
  __syncthreads();
  if (lane == 0) red[wv] = q;
  __syncthreads();
  const float var = (red[0] + red[1] + red[2] + red[3]) * (1.0f / DM);
  const float rs = rsqrtf(var + 1e-5f);

  lx[tid]       = d0 * rs * lnw[tid] + lnb[tid];
  lx[tid + 256] = d1 * rs * lnw[tid + 256] + lnb[tid + 256];
  lx[tid + 512] = d2 * rs * lnw[tid + 512] + lnb[tid + 512];
  __syncthreads();

  const int j = blockIdx.x * 64 + (tid >> 2), sl = tid & 3;
  const int k0 = sl * 192;
  float acc = 0.0f;
  #pragma unroll 4
  for (int k = k0; k < k0 + 192; ++k) acc += lx[k] * dw[(size_t)k * DM + j];
  acc += __shfl_xor(acc, 1);
  acc += __shfl_xor(acc, 2);
  if (sl == 0) pooled[bb * DM + j] = tanhf(acc + db[j]);
}

// ---------------- logits ----------------
__global__ void logits_kernel(const float* __restrict__ pooled,
                              const float* __restrict__ hw,
                              const float* __restrict__ hb,
                              float* __restrict__ out) {
  const int tid = threadIdx.x;
  if (tid < 32) {
    const int bb = tid >> 1, c = tid & 1;
    float acc = hb[c];
    for (int k = 0; k < DM; ++k) acc += pooled[bb * DM + k] * hw[k * 2 + c];
    out[bb * 2 + c] = acc;
  }
}

extern "C" void kernel_launch(void* const* d_in, const int* in_sizes, int n_in,
                              void* d_out, int out_size, void* d_ws, size_t ws_size,
                              hipStream_t stream) {
  const int*   ids   = (const int*)d_in[0];
  const float* wte   = (const float*)d_in[3];
  const float* wpe   = (const float*)d_in[4];
  const float* ln1w  = (const float*)d_in[5];
  const float* ln1b  = (const float*)d_in[6];
  const float* wqkv  = (const float*)d_in[7];
  const float* bqkv  = (const float*)d_in[8];
  const float* wo    = (const float*)d_in[9];
  const float* bo    = (const float*)d_in[10];
  const float* ln2w  = (const float*)d_in[11];
  const float* ln2b  = (const float*)d_in[12];
  const float* wfc   = (const float*)d_in[13];
  const float* bfc   = (const float*)d_in[14];
  const float* wproj = (const float*)d_in[15];
  const float* bproj = (const float*)d_in[16];
  const float* lnfw  = (const float*)d_in[17];
  const float* lnfb  = (const float*)d_in[18];
  const float* dw    = (const float*)d_in[19];
  const float* db    = (const float*)d_in[20];
  const float* hw    = (const float*)d_in[21];
  const float* hb    = (const float*)d_in[22];
  float* out = (float*)d_out;

  const size_t NEED_FULL = 308330496ULL;
  const bool full = ws_size >= NEED_FULL;

  char* ws = (char*)d_ws;
  size_t off = 0;
  auto alloc = [&](size_t bytes) -> void* {
    void* p = ws + off;
    off += (bytes + 255) & ~(size_t)255;
    return p;
  };
  float*  x      = (float*)alloc((size_t)MR * DM * 4);
  bf16_t* h      = (bf16_t*)alloc((size_t)MR * DM * 2);
  bf16_t* qkvb   = (bf16_t*)alloc((size_t)MR * D3 * 2);
  bf16_t* yb     = (bf16_t*)alloc((size_t)MR * DM * 2);
  bf16_t* ub     = (bf16_t*)alloc((size_t)MR * D4 * 2);
  float*  pooled = (float*)alloc((size_t)NB * DM * 4);
  const size_t wmul = full ? NL : 1;
  bf16_t* wqkvT  = (bf16_t*)alloc((size_t)D3 * DM * 2 * wmul);
  bf16_t* woT    = (bf16_t*)alloc((size_t)DM * DM * 2 * wmul);
  bf16_t* wfcT   = (bf16_t*)alloc((size_t)D4 * DM * 2 * wmul);
  bf16_t* wprojT = (bf16_t*)alloc((size_t)DM * D4 * 2 * wmul);

  embed_kernel<<<MR, 256, 0, stream>>>(ids, wte, wpe, x);

  if (full) {
    transpose_all<<<dim3(432, 1, NL), 256, 0, stream>>>(
        wqkv, wo, wfc, wproj, wqkvT, woT, wfcT, wprojT, 0, 0);
  }

  for (int l = 0; l < NL; ++l) {
    if (!full) {
      transpose_all<<<dim3(432, 1, 1), 256, 0, stream>>>(
          wqkv, wo, wfc, wproj, wqkvT, woT, wfcT, wprojT, l, 1);
    }
    bf16_t* qkvT_l = wqkvT + (full ? (size_t)l * D3 * DM : 0);
    bf16_t* woT_l  = woT   + (full ? (size_t)l * DM * DM : 0);
    bf16_t* fcT_l  = wfcT  + (full ? (size_t)l * D4 * DM : 0);
    bf16_t* prT_l  = wprojT+ (full ? (size_t)l * DM * D4 : 0);

    ln_kernel<<<MR / 4, 256, 0, stream>>>(x, ln1w + l * DM, ln1b + l * DM, h);
    gemm8<0, 1><<<dim3(D3 / 256, MR / 256, 1), 512, 0, stream>>>(
        h, qkvT_l, bqkv + (size_t)l * D3, qkvb, nullptr, D3, DM, DM, D3 / 256);
    attn_kernel<<<dim3(TT / 256, NH, NB), 512, 0, stream>>>(qkvb, yb);
    gemm8<2, 2><<<dim3(DM / 256, MR / 256, 2), 512, 0, stream>>>(
        yb, woT_l, bo + (size_t)l * DM, nullptr, x, DM, DM / 2, DM, DM / 256);
    ln_kernel<<<MR / 4, 256, 0, stream>>>(x, ln2w + l * DM, ln2b + l * DM, h);
    gemm8<1, 1><<<dim3(D4 / 256, MR / 256, 1), 512, 0, stream>>>(
        h, fcT_l, bfc + (size_t)l * D4, ub, nullptr, D4, DM, DM, D4 / 256);
    gemm8<2, 2><<<dim3(DM / 256, MR / 256, 2), 512, 0, stream>>>(
        ub, prT_l, bproj + (size_t)l * DM, nullptr, x, DM, D4 / 2, D4, DM / 256);
  }

  pooled_kernel<<<dim3(12, NB), 256, 0, stream>>>(x, lnfw, lnfb, dw, db, pooled);
  logits_kernel<<<1, 64, 0, stream>>>(pooled, hw, hb, out);
}

// Round 7
// 3637.316 us; speedup vs baseline: 1.1454x; 1.0170x over previous
//
#include <hip/hip_runtime.h>
#include <hip/hip_bf16.h>
#include <math.h>

// Problem constants
#define NL 12
#define NH 12
#define DM 768
#define DH 64
#define TT 512
#define NB 16
#define MR (NB*TT)      // 8192 rows
#define D3 (3*DM)       // 2304
#define D4 (4*DM)       // 3072

typedef __bf16 bf16_t;
typedef __attribute__((ext_vector_type(8))) __bf16 bf16x8;
typedef __attribute__((ext_vector_type(4))) __bf16 bf16x4;
typedef __attribute__((ext_vector_type(4))) float f32x4;
typedef __attribute__((ext_vector_type(16))) float f32x16;
typedef __attribute__((ext_vector_type(4))) unsigned int u32x4;

// ---- async global->LDS, 16B per lane. LDS dst is wave-uniform base; HW writes
// lane i at base + i*16. Global src is per-lane. ----
__device__ __forceinline__ void gload_lds16(const void* g, void* l) {
  __builtin_amdgcn_global_load_lds(
      (const __attribute__((address_space(1))) unsigned int*)g,
      (__attribute__((address_space(3))) unsigned int*)l,
      16, 0, 0);
}

__device__ __forceinline__ unsigned pkbf(float a, float b) {
  unsigned short ua = __builtin_bit_cast(unsigned short, (bf16_t)a);
  unsigned short ub = __builtin_bit_cast(unsigned short, (bf16_t)b);
  return (unsigned)ua | ((unsigned)ub << 16);
}

// ---------------- batched weight transpose + f32->bf16 into BLOCKED layout ----------------
// 64k x 128n tiles (32 KB LDS -> ~5 blocks/CU). Output: [ktile t][nb][row r 0..255]
// [chunk p 0..7][8 bf16]; stored chunk p holds original k-chunk (p ^ (r&7)).
// Tiles/layer: qkv 18x12=216 | wo 6x12=72 (->288) | fc 24x12=288 (->576) | proj 6x48=288 (->864)
__global__ __launch_bounds__(256) void transpose_all(
    const float* __restrict__ wqkv, const float* __restrict__ wo,
    const float* __restrict__ wfc, const float* __restrict__ wproj,
    bf16_t* __restrict__ qkvT, bf16_t* __restrict__ woT,
    bf16_t* __restrict__ fcT, bf16_t* __restrict__ projT,
    int l0, int per_layer_out) {
  const int lay = l0 + blockIdx.z;
  int bid = blockIdx.x;
  const float* in; bf16_t* out; int K, N;
  if (bid < 216) {
    in = wqkv + (size_t)lay * DM * D3;
    out = qkvT + (per_layer_out ? 0 : (size_t)lay * D3 * DM);
    K = DM; N = D3;
  } else if (bid < 288) {
    bid -= 216;
    in = wo + (size_t)lay * DM * DM;
    out = woT + (per_layer_out ? 0 : (size_t)lay * DM * DM);
    K = DM; N = DM;
  } else if (bid < 576) {
    bid -= 288;
    in = wfc + (size_t)lay * DM * D4;
    out = fcT + (per_layer_out ? 0 : (size_t)lay * D4 * DM);
    K = DM; N = D4;
  } else {
    bid -= 576;
    in = wproj + (size_t)lay * D4 * DM;
    out = projT + (per_layer_out ? 0 : (size_t)lay * DM * D4);
    K = D4; N = DM;
  }
  const int nx = N >> 7;
  const int n0 = (bid % nx) * 128, k0 = (bid / nx) * 64;
  __shared__ float tile[64][128];   // 32 KB
  const int t = threadIdx.x;
  const int rr = t >> 5, c4 = (t & 31) * 4;
  #pragma unroll
  for (int it = 0; it < 8; ++it) {
    const int row = rr + it * 8;
    *(float4*)&tile[row][c4] = *(const float4*)&in[(size_t)(k0 + row) * N + n0 + c4];
  }
  __syncthreads();
  // thread t: output row n = t&127 (2-lane/bank column reads = free), k-half kh.
  const int n = t & 127, kh = t >> 7;
  const int rg = (n0 & 255) + n;          // row within 256-block (n0 is 128-aligned)
  const int nb = n0 >> 8;
  const int nbN = N >> 8;
  const int x = rg & 7;
  bf16_t* base = out + (((size_t)(k0 >> 6) * nbN + nb) * 256 + rg) * 64;
  #pragma unroll
  for (int p4 = 0; p4 < 4; ++p4) {
    const int c = kh * 4 + p4;            // original k-chunk
    bf16x8 o;
    #pragma unroll
    for (int j = 0; j < 8; ++j) o[j] = (bf16_t)tile[c * 8 + j][n];
    *(bf16x8*)(base + ((c ^ x) << 3)) = o;
  }
}

// ---------------- embedding: wave-per-row, float4 ----------------
__global__ __launch_bounds__(256) void embed_kernel(const int* __restrict__ ids,
                                                    const float* __restrict__ wte,
                                                    const float* __restrict__ wpe,
                                                    float* __restrict__ x) {
  const int lane = threadIdx.x & 63, wv = threadIdx.x >> 6;
  const int row = blockIdx.x * 4 + wv;
  const int t = row & (TT - 1);
  const int id = ids[row];
  const int c = lane * 4;
  const float* wt = wte + (size_t)id * DM;
  const float* wp = wpe + (size_t)t * DM;
  float* xr = x + (size_t)row * DM;
  #pragma unroll
  for (int i = 0; i < 3; ++i) {
    const int cc = c + i * 256;
    float4 a = *(const float4*)&wt[cc];
    float4 b = *(const float4*)&wp[cc];
    a.x += b.x; a.y += b.y; a.z += b.z; a.w += b.w;
    *(float4*)&xr[cc] = a;
  }
}

// ---------------- LayerNorm (f32 in -> bf16 out), one WAVE per row ----------------
__global__ __launch_bounds__(256) void ln_kernel(const float* __restrict__ x,
                                                 const float* __restrict__ w,
                                                 const float* __restrict__ b,
                                                 bf16_t* __restrict__ out) {
  const int lane = threadIdx.x & 63, wv = threadIdx.x >> 6;
  const int row = blockIdx.x * 4 + wv;
  const float* xr = x + (size_t)row * DM;
  const int c = lane * 4;
  float4 v0 = *(const float4*)&xr[c];
  float4 v1 = *(const float4*)&xr[c + 256];
  float4 v2 = *(const float4*)&xr[c + 512];
  float s = v0.x + v0.y + v0.z + v0.w + v1.x + v1.y + v1.z + v1.w
          + v2.x + v2.y + v2.z + v2.w;
  #pragma unroll
  for (int off = 32; off > 0; off >>= 1) s += __shfl_xor(s, off);
  const float mean = s * (1.0f / DM);
  float q = 0.0f;
  q += (v0.x-mean)*(v0.x-mean) + (v0.y-mean)*(v0.y-mean) + (v0.z-mean)*(v0.z-mean) + (v0.w-mean)*(v0.w-mean);
  q += (v1.x-mean)*(v1.x-mean) + (v1.y-mean)*(v1.y-mean) + (v1.z-mean)*(v1.z-mean) + (v1.w-mean)*(v1.w-mean);
  q += (v2.x-mean)*(v2.x-mean) + (v2.y-mean)*(v2.y-mean) + (v2.z-mean)*(v2.z-mean) + (v2.w-mean)*(v2.w-mean);
  #pragma unroll
  for (int off = 32; off > 0; off >>= 1) q += __shfl_xor(q, off);
  const float rs = rsqrtf(q * (1.0f / DM) + 1e-5f);
  bf16_t* o = out + (size_t)row * DM;
  #pragma unroll
  for (int i = 0; i < 3; ++i) {
    const int cc = c + i * 256;
    float4 vv = i == 0 ? v0 : (i == 1 ? v1 : v2);
    float4 ww = *(const float4*)&w[cc];
    float4 bb = *(const float4*)&b[cc];
    bf16x4 ob;
    ob[0] = (bf16_t)((vv.x - mean) * rs * ww.x + bb.x);
    ob[1] = (bf16_t)((vv.y - mean) * rs * ww.y + bb.y);
    ob[2] = (bf16_t)((vv.z - mean) * rs * ww.z + bb.z);
    ob[3] = (bf16_t)((vv.w - mean) * rs * ww.w + bb.w);
    *(bf16x4*)&o[cc] = ob;
  }
}

// =====================================================================
// 256x256 8-phase GEMM (T1 XCD swizzle + T2 swizzle + T3/T4 counted-vmcnt
// + T5 setprio). B operand pre-swizzled+blocked [t][nb][256][8ch].
// SPLITK>1: blockIdx.z covers k-range; EPI2 accumulates via f32 atomic.
// =====================================================================
#define OFF(S, MAT, H) (((((S)*2 + (MAT))*2) + (H)) * 8192)

#define STAGE(S, MAT, H, T) do {                                                \
    const int _r0 = tid >> 3, _r1 = _r0 + 64, _c = tid & 7;                     \
    if ((MAT) == 0) {                                                           \
      const bf16_t* _g0 = A + (size_t)(m0 + ((_r0 >> 6) << 7) + (H)*64 + (_r0 & 63)) * Kstride \
              + (T)*64 + ((_c ^ (_r0 & 7)) << 3);                               \
      const bf16_t* _g1 = A + (size_t)(m0 + ((_r1 >> 6) << 7) + (H)*64 + (_r1 & 63)) * Kstride \
              + (T)*64 + ((_c ^ (_r1 & 7)) << 3);                               \
      gload_lds16(_g0, &lds[OFF(S, 0, H) + (w << 9)]);                          \
      gload_lds16(_g1, &lds[OFF(S, 0, H) + 4096 + (w << 9)]);                   \
    } else {                                                                    \
      const int _gr0 = ((_r0 >> 5) << 6) + (H)*32 + (_r0 & 31);                 \
      const int _gr1 = ((_r1 >> 5) << 6) + (H)*32 + (_r1 & 31);                 \
      const bf16_t* _bb = BTB + (((size_t)(T) * nbN + nb) << 14);               \
      gload_lds16(_bb + (_gr0 << 6) + (_c << 3), &lds[OFF(S, 1, H) + (w << 9)]);        \
      gload_lds16(_bb + (_gr1 << 6) + (_c << 3), &lds[OFF(S, 1, H) + 4096 + (w << 9)]); \
    }                                                                           \
  } while (0)

#define RD_A(S, MH) do {                                                        \
    _Pragma("unroll") for (int _mf = 0; _mf < 4; ++_mf) {                       \
      const int _lr = wr * 64 + _mf * 16 + l15;                                 \
      const int _x = _lr & 7;                                                   \
      af[_mf][0] = *(const bf16x8*)&lds[OFF(S,0,MH) + _lr*64 + ((l4 ^ _x) << 3)];        \
      af[_mf][1] = *(const bf16x8*)&lds[OFF(S,0,MH) + _lr*64 + (((4+l4) ^ _x) << 3)];    \
    } } while (0)

#define RD_B(S, NH) do {                                                        \
    _Pragma("unroll") for (int _nf = 0; _nf < 2; ++_nf) {                       \
      const int _lr = wc * 32 + _nf * 16 + l15;                                 \
      const int _x = _lr & 7;                                                   \
      bfr[_nf][0] = *(const bf16x8*)&lds[OFF(S,1,NH) + _lr*64 + ((l4 ^ _x) << 3)];       \
      bfr[_nf][1] = *(const bf16x8*)&lds[OFF(S,1,NH) + _lr*64 + (((4+l4) ^ _x) << 3)];   \
    } } while (0)

#define MM(MH, NH) do {                                                         \
    __builtin_amdgcn_s_setprio(1);                                              \
    _Pragma("unroll") for (int _ks = 0; _ks < 2; ++_ks)                         \
      _Pragma("unroll") for (int _mf = 0; _mf < 4; ++_mf)                       \
        _Pragma("unroll") for (int _nf = 0; _nf < 2; ++_nf)                     \
          acc[(MH)*4+_mf][(NH)*2+_nf] = __builtin_amdgcn_mfma_f32_16x16x32_bf16(\
              af[_mf][_ks], bfr[_nf][_ks], acc[(MH)*4+_mf][(NH)*2+_nf], 0,0,0); \
    __builtin_amdgcn_s_setprio(0);                                              \
  } while (0)

#define BAR()   __builtin_amdgcn_s_barrier()
#define LGKM0() asm volatile("s_waitcnt lgkmcnt(0)" ::: "memory")
#define LGKM8() asm volatile("s_waitcnt lgkmcnt(8)" ::: "memory")
#define VM6()   asm volatile("s_waitcnt vmcnt(6)" ::: "memory")

// EPI: 0 = +bias -> bf16 ; 1 = +bias, tanh-approx GELU -> bf16 ; 2 = +bias, += f32 resid
template <int EPI, int SPLITK>
__global__ __launch_bounds__(512, 2) void gemm8(const bf16_t* __restrict__ A,
                                                const bf16_t* __restrict__ BTB,
                                                const float* __restrict__ bias,
                                                bf16_t* __restrict__ outb,
                                                float* __restrict__ resid,
                                                int Ndim, int Kdim, int Kstride, int nbN) {
  __shared__ bf16_t lds[65536];   // 128 KB
  const int tid = threadIdx.x, lane = tid & 63, w = tid >> 6;
  const int wr = w >> 2, wc = w & 3;
  const int l15 = lane & 15, l4 = lane >> 4;
  const int zz = (SPLITK > 1) ? blockIdx.z : 0;
  A += (size_t)zz * Kdim;
  BTB += ((size_t)zz * (Kdim >> 6) * nbN) << 14;

  // T1: bijective XCD-aware tile swizzle (m204). All grids here are %8==0 (r8=0).
  const unsigned nwg = gridDim.x * gridDim.y;
  const unsigned orig = blockIdx.y * gridDim.x + blockIdx.x;
  const unsigned q8 = nwg >> 3;
  const unsigned wg = (orig & 7) * q8 + (orig >> 3);
  const int nb = (int)(wg % gridDim.x);
  const int m0 = (int)(wg / gridDim.x) * 256, n0 = nb * 256;
  const int nT = Kdim >> 6, nIter = Kdim >> 7;

  f32x4 acc[8][4] = {};
  bf16x8 af[4][2], bfr[2][2];

  // prologue: slot0 = tile0 (4 half-tiles), slot1 = tile1 (3 of 4; B.h0 staged at ph0)
  STAGE(0, 0, 0, 0); STAGE(0, 1, 0, 0); STAGE(0, 0, 1, 0); STAGE(0, 1, 1, 0);
  asm volatile("s_waitcnt vmcnt(4)" ::: "memory");
  STAGE(1, 0, 0, 1); STAGE(1, 1, 1, 1); STAGE(1, 0, 1, 1);
  asm volatile("s_waitcnt vmcnt(6)" ::: "memory");
  BAR();

  for (int it = 0; it < nIter; ++it) {
    const int t1 = 2 * it + 1;
    int ts0 = 2 * it + 2; if (ts0 >= nT) ts0 -= nT;   // wrap: harmless re-stage
    int ts1 = 2 * it + 3; if (ts1 >= nT) ts1 -= nT;
    // ph0
    RD_A(0, 0); RD_B(0, 0); STAGE(1, 1, 0, t1);
    LGKM8(); BAR(); LGKM0(); MM(0, 0); BAR();
    // ph1
    RD_B(0, 1); STAGE(0, 0, 0, ts0);
    BAR(); LGKM0(); MM(0, 1); BAR();
    // ph2
    RD_A(0, 1); STAGE(0, 1, 1, ts0);
    BAR(); LGKM0(); MM(1, 1); BAR();
    // ph3 ; vmcnt(6) -> slot1 fully visible for ph4-7
    RD_B(0, 0); STAGE(0, 0, 1, ts0);
    BAR(); LGKM0(); MM(1, 0); VM6(); BAR();
    // ph4
    RD_A(1, 0); RD_B(1, 0); STAGE(0, 1, 0, ts0);
    LGKM8(); BAR(); LGKM0(); MM(0, 0); BAR();
    // ph5
    RD_B(1, 1); STAGE(1, 0, 0, ts1);
    BAR(); LGKM0(); MM(0, 1); BAR();
    // ph6
    RD_A(1, 1); STAGE(1, 1, 1, ts1);
    BAR(); LGKM0(); MM(1, 1); BAR();
    // ph7 ; vmcnt(6) -> slot0 fully visible for next ph0-3
    RD_B(1, 0); STAGE(1, 0, 1, ts1);
    BAR(); LGKM0(); MM(1, 0); VM6(); BAR();
  }

  // epilogue
  #pragma unroll
  for (int mf = 0; mf < 8; ++mf) {
    #pragma unroll
    for (int nf = 0; nf < 4; ++nf) {
      const int col = n0 + wc * 64 + nf * 16 + l15;
      const float bv = (SPLITK == 1 || zz == 0) ? bias[col] : 0.0f;
      #pragma unroll
      for (int r = 0; r < 4; ++r) {
        const int row = m0 + wr * 128 + mf * 16 + l4 * 4 + r;
        float v = acc[mf][nf][r] + bv;
        if (EPI == 1) {
          // tanh-approx GELU in sigmoid form: u*sigmoid(1.59577(u+0.044715u^3))
          const float z2 = 1.5957692f * v + 0.07135481f * v * v * v;
          v = v / (1.0f + __expf(-z2));
        }
        if (EPI == 2) {
          const size_t idx2 = (size_t)row * Ndim + col;
          if (SPLITK > 1) unsafeAtomicAdd(&resid[idx2], v);
          else            resid[idx2] += v;
        } else {
          outb[(size_t)row * Ndim + col] = (bf16_t)v;
        }
      }
    }
  }
}

// ---------------- fused flash attention (2 blocks/CU via launch_bounds) ----------------
__global__ __launch_bounds__(512, 4) void attn_kernel(const bf16_t* __restrict__ qkv,
                                                      bf16_t* __restrict__ y) {
  const int qt = blockIdx.x, hh = blockIdx.y, bb = blockIdx.z;
  const int tid = threadIdx.x, lane = tid & 63, w = tid >> 6;
  const int l31 = lane & 31, hiL = lane >> 5;

  __shared__ bf16_t smem[18432];
  bf16_t* Kbuf = smem;
  bf16_t* Vbuf = smem + 8192;

  const bf16_t* kb = qkv + (size_t)(bb * TT) * D3 + DM + hh * 64;
  const bf16_t* vb = qkv + (size_t)(bb * TT) * D3 + 2 * DM + hh * 64;

  const bf16_t* qptr = qkv + (size_t)(bb * TT + qt * 256 + w * 32 + l31) * D3 + hh * 64 + hiL * 8;
  bf16x8 qreg[4];
  #pragma unroll
  for (int ks = 0; ks < 4; ++ks) {
    bf16x8 v = *(const bf16x8*)(qptr + ks * 16);
    #pragma unroll
    for (int j = 0; j < 8; ++j) qreg[ks][j] = (bf16_t)((float)v[j] * 0.125f);
  }

  const int sr = tid >> 3, sc = tid & 7;
  #define ATTN_STAGE(KT, BUF)                                                     \
    {                                                                             \
      gload_lds16(kb + (size_t)((KT) * 64 + sr) * D3 + ((sc ^ (sr & 7)) * 8),     \
                  Kbuf + (BUF) * 4096 + (w << 9));                                \
      bf16x8 tv;                                                                  \
      _Pragma("unroll")                                                           \
      for (int j = 0; j < 8; ++j) tv[j] = vb[(size_t)((KT) * 64 + w * 8 + j) * D3 + lane]; \
      *(bf16x8*)&Vbuf[(BUF) * 4096 + lane * 64 + ((w ^ (lane & 7)) << 3)] = tv;   \
    }

  ATTN_STAGE(0, 0);

  f32x16 o0 = 0.0f, o1 = 0.0f;
  float m = -INFINITY, l = 0.0f;

  for (int kt = 0; kt < 8; ++kt) {
    __syncthreads();
    if (kt < 7) ATTN_STAGE(kt + 1, (kt + 1) & 1);

    const bf16_t* Kb = Kbuf + (kt & 1) * 4096;
    const bf16_t* Vb = Vbuf + (kt & 1) * 4096;

    f32x16 st0 = 0.0f, st1 = 0.0f;
    #pragma unroll
    for (int ks = 0; ks < 4; ++ks) {
      const int ch = (ks * 2 + hiL) ^ (l31 & 7);
      bf16x8 kf0 = *(const bf16x8*)&Kb[l31 * 64 + ch * 8];
      bf16x8 kf1 = *(const bf16x8*)&Kb[(32 + l31) * 64 + ch * 8];
      st0 = __builtin_amdgcn_mfma_f32_32x32x16_bf16(kf0, qreg[ks], st0, 0, 0, 0);
      st1 = __builtin_amdgcn_mfma_f32_32x32x16_bf16(kf1, qreg[ks], st1, 0, 0, 0);
    }

    float tm = fmaxf(st0[0], st1[0]);
    #pragma unroll
    for (int i = 1; i < 16; ++i) tm = fmaxf(tm, fmaxf(st0[i], st1[i]));
    tm = fmaxf(tm, __shfl_xor(tm, 32));
    const float mnew = fmaxf(m, tm);
    const float al = __expf(m - mnew);
    #pragma unroll
    for (int i = 0; i < 16; ++i) st0[i] = __expf(st0[i] - mnew);
    #pragma unroll
    for (int i = 0; i < 16; ++i) st1[i] = __expf(st1[i] - mnew);
    float ps = 0.0f;
    #pragma unroll
    for (int i = 0; i < 16; ++i) ps += st0[i] + st1[i];
    ps += __shfl_xor(ps, 32);
    l = l * al + ps;
    m = mnew;
    #pragma unroll
    for (int i = 0; i < 16; ++i) { o0[i] *= al; o1[i] *= al; }

    #pragma unroll
    for (int g = 0; g < 2; ++g) {
      unsigned u0, u1, u2, u3, u4, u5, u6, u7;
      if (g == 0) {
        u0 = pkbf(st0[0], st0[1]);   u1 = pkbf(st0[2], st0[3]);
        u2 = pkbf(st0[4], st0[5]);   u3 = pkbf(st0[6], st0[7]);
        u4 = pkbf(st0[8], st0[9]);   u5 = pkbf(st0[10], st0[11]);
        u6 = pkbf(st0[12], st0[13]); u7 = pkbf(st0[14], st0[15]);
      } else {
        u0 = pkbf(st1[0], st1[1]);   u1 = pkbf(st1[2], st1[3]);
        u2 = pkbf(st1[4], st1[5]);   u3 = pkbf(st1[6], st1[7]);
        u4 = pkbf(st1[8], st1[9]);   u5 = pkbf(st1[10], st1[11]);
        u6 = pkbf(st1[12], st1[13]); u7 = pkbf(st1[14], st1[15]);
      }
      #pragma unroll
      for (int ks2 = 0; ks2 < 2; ++ks2) {
        const unsigned a0 = ks2 ? u4 : u0, a1 = ks2 ? u5 : u1;
        const unsigned a2 = ks2 ? u6 : u2, a3 = ks2 ? u7 : u3;
        const unsigned own0 = hiL ? a2 : a0, own1 = hiL ? a3 : a1;
        const unsigned snd0 = hiL ? a0 : a2, snd1 = hiL ? a1 : a3;
        const unsigned rcv0 = (unsigned)__shfl_xor((int)snd0, 32);
        const unsigned rcv1 = (unsigned)__shfl_xor((int)snd1, 32);
        u32x4 fw;
        fw[0] = hiL ? rcv0 : own0;
        fw[1] = hiL ? rcv1 : own1;
        fw[2] = hiL ? own0 : rcv0;
        fw[3] = hiL ? own1 : rcv1;
        const bf16x8 pa = __builtin_bit_cast(bf16x8, fw);
        const int chv = (g * 4 + ks2 * 2 + hiL) ^ (l31 & 7);
        bf16x8 vf0 = *(const bf16x8*)&Vb[l31 * 64 + chv * 8];
        bf16x8 vf1 = *(const bf16x8*)&Vb[(32 + l31) * 64 + chv * 8];
        o0 = __builtin_amdgcn_mfma_f32_32x32x16_bf16(vf0, pa, o0, 0, 0, 0);
        o1 = __builtin_amdgcn_mfma_f32_32x32x16_bf16(vf1, pa, o1, 0, 0, 0);
      }
    }
  }

  __syncthreads();
  const float rl = 1.0f / l;
  bf16_t* Ob = smem;
  #pragma unroll
  for (int reg = 0; reg < 16; ++reg) {
    const int drow = (reg & 3) + 8 * (reg >> 2) + 4 * hiL;
    Ob[(w * 32 + l31) * 72 + drow]      = (bf16_t)(o0[reg] * rl);
    Ob[(w * 32 + l31) * 72 + 32 + drow] = (bf16_t)(o1[reg] * rl);
  }
  __syncthreads();
  const int qrow = tid >> 1, half = tid & 1;
  bf16_t* yp = y + (size_t)(bb * TT + qt * 256 + qrow) * DM + hh * 64 + half * 32;
  const bf16_t* obp = &Ob[qrow * 72 + half * 32];
  *(bf16x8*)(yp)      = *(const bf16x8*)(obp);
  *(bf16x8*)(yp + 8)  = *(const bf16x8*)(obp + 8);
  *(bf16x8*)(yp + 16) = *(const bf16x8*)(obp + 16);
  *(bf16x8*)(yp + 24) = *(const bf16x8*)(obp + 24);
  #undef ATTN_STAGE
}

// ---------------- final LN (CLS) + dense + tanh -> pooled ----------------
__global__ __launch_bounds__(256) void pooled_kernel(const float* __restrict__ x,
                                                     const float* __restrict__ lnw,
                                                     const float* __restrict__ lnb,
                                                     const float* __restrict__ dw,
                                                     const float* __restrict__ db,
                                                     float* __restrict__ pooled) {
  const int bb = blockIdx.y, tid = threadIdx.x;
  const int lane = tid & 63, wv = tid >> 6;
  const float* xr = x + (size_t)(bb * TT) * DM;
  float v0 = xr[tid], v1 = xr[tid + 256], v2 = xr[tid + 512];
  __shared__ float red[8];
  __shared__ float lx[DM];
  float s = v0 + v1 + v2;
  #pragma unroll
  for (int off = 32; off > 0; off >>= 1) s += __shfl_down(s, off);
  if (lane == 0) red[wv] = s;
  __syncthreads();
  const float mean = (red[0] + red[1] + red[2] + red[3]) * (1.0f / DM);
  const float d0 = v0 - mean, d1 = v1 - mean, d2 = v2 - mean;
  float q = d0 * d0 + d1 * d1 + d2 * d2;
  #pragma unroll
  for (int off = 32; off > 0; off >>= 1) q += __shfl_down(q, off);
  __syncthreads();
  if (lane == 0) red[wv] = q;
  __syncthreads();
  const float var = (red[0] + red[1] + red[2] + red[3]) * (1.0f / DM);
  const float rs = rsqrtf(var + 1e-5f);

  lx[tid]       = d0 * rs * lnw[tid] + lnb[tid];
  lx[tid + 256] = d1 * rs * lnw[tid + 256] + lnb[tid + 256];
  lx[tid + 512] = d2 * rs * lnw[tid + 512] + lnb[tid + 512];
  __syncthreads();

  const int j = blockIdx.x * 64 + (tid >> 2), sl = tid & 3;
  const int k0 = sl * 192;
  float acc = 0.0f;
  #pragma unroll 4
  for (int k = k0; k < k0 + 192; ++k) acc += lx[k] * dw[(size_t)k * DM + j];
  acc += __shfl_xor(acc, 1);
  acc += __shfl_xor(acc, 2);
  if (sl == 0) pooled[bb * DM + j] = tanhf(acc + db[j]);
}

// ---------------- logits ----------------
__global__ void logits_kernel(const float* __restrict__ pooled,
                              const float* __restrict__ hw,
                              const float* __restrict__ hb,
                              float* __restrict__ out) {
  const int tid = threadIdx.x;
  if (tid < 32) {
    const int bb = tid >> 1, c = tid & 1;
    float acc = hb[c];
    for (int k = 0; k < DM; ++k) acc += pooled[bb * DM + k] * hw[k * 2 + c];
    out[bb * 2 + c] = acc;
  }
}

extern "C" void kernel_launch(void* const* d_in, const int* in_sizes, int n_in,
                              void* d_out, int out_size, void* d_ws, size_t ws_size,
                              hipStream_t stream) {
  const int*   ids   = (const int*)d_in[0];
  const float* wte   = (const float*)d_in[3];
  const float* wpe   = (const float*)d_in[4];
  const float* ln1w  = (const float*)d_in[5];
  const float* ln1b  = (const float*)d_in[6];
  const float* wqkv  = (const float*)d_in[7];
  const float* bqkv  = (const float*)d_in[8];
  const float* wo    = (const float*)d_in[9];
  const float* bo    = (const float*)d_in[10];
  const float* ln2w  = (const float*)d_in[11];
  const float* ln2b  = (const float*)d_in[12];
  const float* wfc   = (const float*)d_in[13];
  const float* bfc   = (const float*)d_in[14];
  const float* wproj = (const float*)d_in[15];
  const float* bproj = (const float*)d_in[16];
  const float* lnfw  = (const float*)d_in[17];
  const float* lnfb  = (const float*)d_in[18];
  const float* dw    = (const float*)d_in[19];
  const float* db    = (const float*)d_in[20];
  const float* hw    = (const float*)d_in[21];
  const float* hb    = (const float*)d_in[22];
  float* out = (float*)d_out;

  const size_t NEED_FULL = 308330496ULL;
  const bool full = ws_size >= NEED_FULL;

  char* ws = (char*)d_ws;
  size_t off = 0;
  auto alloc = [&](size_t bytes) -> void* {
    void* p = ws + off;
    off += (bytes + 255) & ~(size_t)255;
    return p;
  };
  float*  x      = (float*)alloc((size_t)MR * DM * 4);
  bf16_t* h      = (bf16_t*)alloc((size_t)MR * DM * 2);
  bf16_t* qkvb   = (bf16_t*)alloc((size_t)MR * D3 * 2);
  bf16_t* yb     = (bf16_t*)alloc((size_t)MR * DM * 2);
  bf16_t* ub     = (bf16_t*)alloc((size_t)MR * D4 * 2);
  float*  pooled = (float*)alloc((size_t)NB * DM * 4);
  const size_t wmul = full ? NL : 1;
  bf16_t* wqkvT  = (bf16_t*)alloc((size_t)D3 * DM * 2 * wmul);
  bf16_t* woT    = (bf16_t*)alloc((size_t)DM * DM * 2 * wmul);
  bf16_t* wfcT   = (bf16_t*)alloc((size_t)D4 * DM * 2 * wmul);
  bf16_t* wprojT = (bf16_t*)alloc((size_t)DM * D4 * 2 * wmul);

  embed_kernel<<<MR / 4, 256, 0, stream>>>(ids, wte, wpe, x);

  if (full) {
    transpose_all<<<dim3(864, 1, NL), 256, 0, stream>>>(
        wqkv, wo, wfc, wproj, wqkvT, woT, wfcT, wprojT, 0, 0);
  }

  for (int l = 0; l < NL; ++l) {
    if (!full) {
      transpose_all<<<dim3(864, 1, 1), 256, 0, stream>>>(
          wqkv, wo, wfc, wproj, wqkvT, woT, wfcT, wprojT, l, 1);
    }
    bf16_t* qkvT_l = wqkvT + (full ? (size_t)l * D3 * DM : 0);
    bf16_t* woT_l  = woT   + (full ? (size_t)l * DM * DM : 0);
    bf16_t* fcT_l  = wfcT  + (full ? (size_t)l * D4 * DM : 0);
    bf16_t* prT_l  = wprojT+ (full ? (size_t)l * DM * D4 : 0);

    ln_kernel<<<MR / 4, 256, 0, stream>>>(x, ln1w + l * DM, ln1b + l * DM, h);
    gemm8<0, 1><<<dim3(D3 / 256, MR / 256, 1), 512, 0, stream>>>(
        h, qkvT_l, bqkv + (size_t)l * D3, qkvb, nullptr, D3, DM, DM, D3 / 256);
    attn_kernel<<<dim3(TT / 256, NH, NB), 512, 0, stream>>>(qkvb, yb);
    gemm8<2, 2><<<dim3(DM / 256, MR / 256, 2), 512, 0, stream>>>(
        yb, woT_l, bo + (size_t)l * DM, nullptr, x, DM, DM / 2, DM, DM / 256);
    ln_kernel<<<MR / 4, 256, 0, stream>>>(x, ln2w + l * DM, ln2b + l * DM, h);
    gemm8<1, 1><<<dim3(D4 / 256, MR / 256, 1), 512, 0, stream>>>(
        h, fcT_l, bfc + (size_t)l * D4, ub, nullptr, D4, DM, DM, D4 / 256);
    gemm8<2, 2><<<dim3(DM / 256, MR / 256, 2), 512, 0, stream>>>(
        ub, prT_l, bproj + (size_t)l * DM, nullptr, x, DM, D4 / 2, D4, DM / 256);
  }

  pooled_kernel<<<dim3(12, NB), 256, 0, stream>>>(x, lnfw, lnfb, dw, db, pooled);
  logits_kernel<<<1, 64, 0, stream>>>(pooled, hw, hb, out);
}

// Round 8
// 3211.115 us; speedup vs baseline: 1.2974x; 1.1327x over previous
//
#include <hip/hip_runtime.h>
#include <hip/hip_bf16.h>
#include <math.h>

// Problem constants
#define NL 12
#define NH 12
#define DM 768
#define DH 64
#define TT 512
#define NB 16
#define MR (NB*TT)      // 8192 rows
#define D3 (3*DM)       // 2304
#define D4 (4*DM)       // 3072

typedef __bf16 bf16_t;
typedef __attribute__((ext_vector_type(8))) __bf16 bf16x8;
typedef __attribute__((ext_vector_type(4))) __bf16 bf16x4;
typedef __attribute__((ext_vector_type(4))) float f32x4;
typedef __attribute__((ext_vector_type(16))) float f32x16;
typedef __attribute__((ext_vector_type(4))) unsigned int u32x4;

__device__ __forceinline__ void gload_lds16(const void* g, void* l) {
  __builtin_amdgcn_global_load_lds(
      (const __attribute__((address_space(1))) unsigned int*)g,
      (__attribute__((address_space(3))) unsigned int*)l,
      16, 0, 0);
}

__device__ __forceinline__ unsigned pkbf(float a, float b) {
  unsigned short ua = __builtin_bit_cast(unsigned short, (bf16_t)a);
  unsigned short ub = __builtin_bit_cast(unsigned short, (bf16_t)b);
  return (unsigned)ua | ((unsigned)ub << 16);
}

// ---------------- batched weight transpose + f32->bf16 into BLOCKED layout ----------------
// 64k x 128n tiles. Output [ktile][nb][row 0..255][chunk p][8 bf16]; stored chunk p
// holds original k-chunk (p ^ (row&7)). XOR applied on LDS READ side so GLOBAL
// WRITES are fully contiguous (lane t -> row t>>1, 64B half t&1).
__global__ __launch_bounds__(256) void transpose_all(
    const float* __restrict__ wqkv, const float* __restrict__ wo,
    const float* __restrict__ wfc, const float* __restrict__ wproj,
    bf16_t* __restrict__ qkvT, bf16_t* __restrict__ woT,
    bf16_t* __restrict__ fcT, bf16_t* __restrict__ projT,
    int l0, int per_layer_out) {
  const int lay = l0 + blockIdx.z;
  int bid = blockIdx.x;
  const float* in; bf16_t* out; int N;
  if (bid < 216) {
    in = wqkv + (size_t)lay * DM * D3;
    out = qkvT + (per_layer_out ? 0 : (size_t)lay * D3 * DM);
    N = D3;
  } else if (bid < 288) {
    bid -= 216;
    in = wo + (size_t)lay * DM * DM;
    out = woT + (per_layer_out ? 0 : (size_t)lay * DM * DM);
    N = DM;
  } else if (bid < 576) {
    bid -= 288;
    in = wfc + (size_t)lay * DM * D4;
    out = fcT + (per_layer_out ? 0 : (size_t)lay * D4 * DM);
    N = D4;
  } else {
    bid -= 576;
    in = wproj + (size_t)lay * D4 * DM;
    out = projT + (per_layer_out ? 0 : (size_t)lay * DM * D4);
    N = DM;
  }
  const int nx = N >> 7;
  const int n0 = (bid % nx) * 128, k0 = (bid / nx) * 64;
  __shared__ float tile[64][128];   // 32 KB
  const int t = threadIdx.x;
  const int rr = t >> 5, c4 = (t & 31) * 4;
  #pragma unroll
  for (int it = 0; it < 8; ++it) {
    const int row = rr + it * 8;
    *(float4*)&tile[row][c4] = *(const float4*)&in[(size_t)(k0 + row) * N + n0 + c4];
  }
  __syncthreads();
  // lane t: output row n = t>>1, 64B half kh = t&1 -> consecutive lanes write
  // consecutive 64B -> perfectly coalesced. XOR permutes the LDS source chunk.
  const int n = t >> 1, kh = t & 1;
  const int rg = (n0 & 255) + n;
  const int nb = n0 >> 8;
  const int nbN = N >> 8;
  const int x = rg & 7;
  bf16_t* base = out + (((size_t)(k0 >> 6) * nbN + nb) * 256 + rg) * 64 + kh * 32;
  #pragma unroll
  for (int p4 = 0; p4 < 4; ++p4) {
    const int c = (kh * 4 + p4) ^ x;      // source k-chunk for stored position
    bf16x8 o;
    #pragma unroll
    for (int j = 0; j < 8; ++j) o[j] = (bf16_t)tile[c * 8 + j][n];
    *(bf16x8*)(base + (p4 << 3)) = o;
  }
}

// ---------------- embedding: wave-per-row, float4 ----------------
__global__ __launch_bounds__(256) void embed_kernel(const int* __restrict__ ids,
                                                    const float* __restrict__ wte,
                                                    const float* __restrict__ wpe,
                                                    float* __restrict__ x) {
  const int lane = threadIdx.x & 63, wv = threadIdx.x >> 6;
  const int row = blockIdx.x * 4 + wv;
  const int t = row & (TT - 1);
  const int id = ids[row];
  const int c = lane * 4;
  const float* wt = wte + (size_t)id * DM;
  const float* wp = wpe + (size_t)t * DM;
  float* xr = x + (size_t)row * DM;
  #pragma unroll
  for (int i = 0; i < 3; ++i) {
    const int cc = c + i * 256;
    float4 a = *(const float4*)&wt[cc];
    float4 b = *(const float4*)&wp[cc];
    a.x += b.x; a.y += b.y; a.z += b.z; a.w += b.w;
    *(float4*)&xr[cc] = a;
  }
}

// ---------------- LayerNorm, one WAVE per row; MERGE: x += pa_z0 + pa_z1 first ----------------
template <int MERGE>
__global__ __launch_bounds__(256) void ln_kernel(float* __restrict__ x,
                                                 const float* __restrict__ pa,
                                                 const float* __restrict__ w,
                                                 const float* __restrict__ b,
                                                 bf16_t* __restrict__ out) {
  const int lane = threadIdx.x & 63, wv = threadIdx.x >> 6;
  const int row = blockIdx.x * 4 + wv;
  float* xr = x + (size_t)row * DM;
  const int c = lane * 4;
  float4 v0 = *(const float4*)&xr[c];
  float4 v1 = *(const float4*)&xr[c + 256];
  float4 v2 = *(const float4*)&xr[c + 512];
  if (MERGE) {
    const float* p0 = pa + (size_t)row * DM;
    const float* p1 = pa + (size_t)MR * DM + (size_t)row * DM;
    #pragma unroll
    for (int i = 0; i < 3; ++i) {
      const int cc = c + i * 256;
      float4 a = *(const float4*)&p0[cc];
      float4 bfv = *(const float4*)&p1[cc];
      float4& v = i == 0 ? v0 : (i == 1 ? v1 : v2);
      v.x += a.x + bfv.x; v.y += a.y + bfv.y; v.z += a.z + bfv.z; v.w += a.w + bfv.w;
      *(float4*)&xr[cc] = v;
    }
  }
  float s = v0.x + v0.y + v0.z + v0.w + v1.x + v1.y + v1.z + v1.w
          + v2.x + v2.y + v2.z + v2.w;
  #pragma unroll
  for (int off = 32; off > 0; off >>= 1) s += __shfl_xor(s, off);
  const float mean = s * (1.0f / DM);
  float q = 0.0f;
  q += (v0.x-mean)*(v0.x-mean) + (v0.y-mean)*(v0.y-mean) + (v0.z-mean)*(v0.z-mean) + (v0.w-mean)*(v0.w-mean);
  q += (v1.x-mean)*(v1.x-mean) + (v1.y-mean)*(v1.y-mean) + (v1.z-mean)*(v1.z-mean) + (v1.w-mean)*(v1.w-mean);
  q += (v2.x-mean)*(v2.x-mean) + (v2.y-mean)*(v2.y-mean) + (v2.z-mean)*(v2.z-mean) + (v2.w-mean)*(v2.w-mean);
  #pragma unroll
  for (int off = 32; off > 0; off >>= 1) q += __shfl_xor(q, off);
  const float rs = rsqrtf(q * (1.0f / DM) + 1e-5f);
  bf16_t* o = out + (size_t)row * DM;
  #pragma unroll
  for (int i = 0; i < 3; ++i) {
    const int cc = c + i * 256;
    float4 vv = i == 0 ? v0 : (i == 1 ? v1 : v2);
    float4 ww = *(const float4*)&w[cc];
    float4 bb = *(const float4*)&b[cc];
    bf16x4 ob;
    ob[0] = (bf16_t)((vv.x - mean) * rs * ww.x + bb.x);
    ob[1] = (bf16_t)((vv.y - mean) * rs * ww.y + bb.y);
    ob[2] = (bf16_t)((vv.z - mean) * rs * ww.z + bb.z);
    ob[3] = (bf16_t)((vv.w - mean) * rs * ww.w + bb.w);
    *(bf16x4*)&o[cc] = ob;
  }
}

// =====================================================================
// 256x256 8-phase GEMM (T1+T2+T3/T4+T5). B pre-swizzled+blocked [t][nb][256][8ch].
// SPLITK>1: blockIdx.z covers k-range. EPI2: ATOM=1 -> f32 atomicAdd into resid;
// ATOM=0 -> plain store of partial into resid[z*MR*Ndim + ...] (merged by LN).
// =====================================================================
#define OFF(S, MAT, H) (((((S)*2 + (MAT))*2) + (H)) * 8192)

#define STAGE(S, MAT, H, T) do {                                                \
    const int _r0 = tid >> 3, _r1 = _r0 + 64, _c = tid & 7;                     \
    if ((MAT) == 0) {                                                           \
      const bf16_t* _g0 = A + (size_t)(m0 + ((_r0 >> 6) << 7) + (H)*64 + (_r0 & 63)) * Kstride \
              + (T)*64 + ((_c ^ (_r0 & 7)) << 3);                               \
      const bf16_t* _g1 = A + (size_t)(m0 + ((_r1 >> 6) << 7) + (H)*64 + (_r1 & 63)) * Kstride \
              + (T)*64 + ((_c ^ (_r1 & 7)) << 3);                               \
      gload_lds16(_g0, &lds[OFF(S, 0, H) + (w << 9)]);                          \
      gload_lds16(_g1, &lds[OFF(S, 0, H) + 4096 + (w << 9)]);                   \
    } else {                                                                    \
      const int _gr0 = ((_r0 >> 5) << 6) + (H)*32 + (_r0 & 31);                 \
      const int _gr1 = ((_r1 >> 5) << 6) + (H)*32 + (_r1 & 31);                 \
      const bf16_t* _bb = BTB + (((size_t)(T) * nbN + nb) << 14);               \
      gload_lds16(_bb + (_gr0 << 6) + (_c << 3), &lds[OFF(S, 1, H) + (w << 9)]);        \
      gload_lds16(_bb + (_gr1 << 6) + (_c << 3), &lds[OFF(S, 1, H) + 4096 + (w << 9)]); \
    }                                                                           \
  } while (0)

#define RD_A(S, MH) do {                                                        \
    _Pragma("unroll") for (int _mf = 0; _mf < 4; ++_mf) {                       \
      const int _lr = wr * 64 + _mf * 16 + l15;                                 \
      const int _x = _lr & 7;                                                   \
      af[_mf][0] = *(const bf16x8*)&lds[OFF(S,0,MH) + _lr*64 + ((l4 ^ _x) << 3)];        \
      af[_mf][1] = *(const bf16x8*)&lds[OFF(S,0,MH) + _lr*64 + (((4+l4) ^ _x) << 3)];    \
    } } while (0)

#define RD_B(S, NH) do {                                                        \
    _Pragma("unroll") for (int _nf = 0; _nf < 2; ++_nf) {                       \
      const int _lr = wc * 32 + _nf * 16 + l15;                                 \
      const int _x = _lr & 7;                                                   \
      bfr[_nf][0] = *(const bf16x8*)&lds[OFF(S,1,NH) + _lr*64 + ((l4 ^ _x) << 3)];       \
      bfr[_nf][1] = *(const bf16x8*)&lds[OFF(S,1,NH) + _lr*64 + (((4+l4) ^ _x) << 3)];   \
    } } while (0)

#define MM(MH, NH) do {                                                         \
    __builtin_amdgcn_s_setprio(1);                                              \
    _Pragma("unroll") for (int _ks = 0; _ks < 2; ++_ks)                         \
      _Pragma("unroll") for (int _mf = 0; _mf < 4; ++_mf)                       \
        _Pragma("unroll") for (int _nf = 0; _nf < 2; ++_nf)                     \
          acc[(MH)*4+_mf][(NH)*2+_nf] = __builtin_amdgcn_mfma_f32_16x16x32_bf16(\
              af[_mf][_ks], bfr[_nf][_ks], acc[(MH)*4+_mf][(NH)*2+_nf], 0,0,0); \
    __builtin_amdgcn_s_setprio(0);                                              \
  } while (0)

#define BAR()   __builtin_amdgcn_s_barrier()
#define LGKM0() asm volatile("s_waitcnt lgkmcnt(0)" ::: "memory")
#define LGKM8() asm volatile("s_waitcnt lgkmcnt(8)" ::: "memory")
#define VM6()   asm volatile("s_waitcnt vmcnt(6)" ::: "memory")

// EPI: 0 = +bias -> bf16 ; 1 = +bias, tanh-approx GELU -> bf16 ; 2 = resid (see above)
template <int EPI, int SPLITK, int ATOM>
__global__ __launch_bounds__(512, 2) void gemm8(const bf16_t* __restrict__ A,
                                                const bf16_t* __restrict__ BTB,
                                                const float* __restrict__ bias,
                                                bf16_t* __restrict__ outb,
                                                float* __restrict__ resid,
                                                int Ndim, int Kdim, int Kstride, int nbN) {
  __shared__ bf16_t lds[65536];   // 128 KB
  const int tid = threadIdx.x, lane = tid & 63, w = tid >> 6;
  const int wr = w >> 2, wc = w & 3;
  const int l15 = lane & 15, l4 = lane >> 4;
  const int zz = (SPLITK > 1) ? blockIdx.z : 0;
  A += (size_t)zz * Kdim;
  BTB += ((size_t)zz * (Kdim >> 6) * nbN) << 14;

  // T1: bijective XCD-aware tile swizzle (m204). All grids here are %8==0.
  const unsigned nwg = gridDim.x * gridDim.y;
  const unsigned orig = blockIdx.y * gridDim.x + blockIdx.x;
  const unsigned q8 = nwg >> 3;
  const unsigned wg = (orig & 7) * q8 + (orig >> 3);
  const int nb = (int)(wg % gridDim.x);
  const int m0 = (int)(wg / gridDim.x) * 256, n0 = nb * 256;
  const int nT = Kdim >> 6, nIter = Kdim >> 7;

  f32x4 acc[8][4] = {};
  bf16x8 af[4][2], bfr[2][2];

  STAGE(0, 0, 0, 0); STAGE(0, 1, 0, 0); STAGE(0, 0, 1, 0); STAGE(0, 1, 1, 0);
  asm volatile("s_waitcnt vmcnt(4)" ::: "memory");
  STAGE(1, 0, 0, 1); STAGE(1, 1, 1, 1); STAGE(1, 0, 1, 1);
  asm volatile("s_waitcnt vmcnt(6)" ::: "memory");
  BAR();

  for (int it = 0; it < nIter; ++it) {
    const int t1 = 2 * it + 1;
    int ts0 = 2 * it + 2; if (ts0 >= nT) ts0 -= nT;
    int ts1 = 2 * it + 3; if (ts1 >= nT) ts1 -= nT;
    RD_A(0, 0); RD_B(0, 0); STAGE(1, 1, 0, t1);
    LGKM8(); BAR(); LGKM0(); MM(0, 0); BAR();
    RD_B(0, 1); STAGE(0, 0, 0, ts0);
    BAR(); LGKM0(); MM(0, 1); BAR();
    RD_A(0, 1); STAGE(0, 1, 1, ts0);
    BAR(); LGKM0(); MM(1, 1); BAR();
    RD_B(0, 0); STAGE(0, 0, 1, ts0);
    BAR(); LGKM0(); MM(1, 0); VM6(); BAR();
    RD_A(1, 0); RD_B(1, 0); STAGE(0, 1, 0, ts0);
    LGKM8(); BAR(); LGKM0(); MM(0, 0); BAR();
    RD_B(1, 1); STAGE(1, 0, 0, ts1);
    BAR(); LGKM0(); MM(0, 1); BAR();
    RD_A(1, 1); STAGE(1, 1, 1, ts1);
    BAR(); LGKM0(); MM(1, 1); BAR();
    RD_B(1, 0); STAGE(1, 0, 1, ts1);
    BAR(); LGKM0(); MM(1, 0); VM6(); BAR();
  }

  // epilogue
  #pragma unroll
  for (int mf = 0; mf < 8; ++mf) {
    #pragma unroll
    for (int nf = 0; nf < 4; ++nf) {
      const int col = n0 + wc * 64 + nf * 16 + l15;
      const float bv = (SPLITK == 1 || zz == 0) ? bias[col] : 0.0f;
      #pragma unroll
      for (int r = 0; r < 4; ++r) {
        const int row = m0 + wr * 128 + mf * 16 + l4 * 4 + r;
        float v = acc[mf][nf][r] + bv;
        if (EPI == 1) {
          const float z2 = 1.5957692f * v + 0.07135481f * v * v * v;
          v = v / (1.0f + __expf(-z2));
        }
        if (EPI == 2) {
          if (SPLITK > 1 && ATOM == 0) {
            resid[(size_t)zz * MR * Ndim + (size_t)row * Ndim + col] = v;
          } else if (SPLITK > 1) {
            unsafeAtomicAdd(&resid[(size_t)row * Ndim + col], v);
          } else {
            resid[(size_t)row * Ndim + col] += v;
          }
        } else {
          outb[(size_t)row * Ndim + col] = (bf16_t)v;
        }
      }
    }
  }
}

// ---------------- fused flash attention (unchanged from round 7) ----------------
__global__ __launch_bounds__(512, 4) void attn_kernel(const bf16_t* __restrict__ qkv,
                                                      bf16_t* __restrict__ y) {
  const int qt = blockIdx.x, hh = blockIdx.y, bb = blockIdx.z;
  const int tid = threadIdx.x, lane = tid & 63, w = tid >> 6;
  const int l31 = lane & 31, hiL = lane >> 5;

  __shared__ bf16_t smem[18432];
  bf16_t* Kbuf = smem;
  bf16_t* Vbuf = smem + 8192;

  const bf16_t* kb = qkv + (size_t)(bb * TT) * D3 + DM + hh * 64;
  const bf16_t* vb = qkv + (size_t)(bb * TT) * D3 + 2 * DM + hh * 64;

  const bf16_t* qptr = qkv + (size_t)(bb * TT + qt * 256 + w * 32 + l31) * D3 + hh * 64 + hiL * 8;
  bf16x8 qreg[4];
  #pragma unroll
  for (int ks = 0; ks < 4; ++ks) {
    bf16x8 v = *(const bf16x8*)(qptr + ks * 16);
    #pragma unroll
    for (int j = 0; j < 8; ++j) qreg[ks][j] = (bf16_t)((float)v[j] * 0.125f);
  }

  const int sr = tid >> 3, sc = tid & 7;
  #define ATTN_STAGE(KT, BUF)                                                     \
    {                                                                             \
      gload_lds16(kb + (size_t)((KT) * 64 + sr) * D3 + ((sc ^ (sr & 7)) * 8),     \
                  Kbuf + (BUF) * 4096 + (w << 9));                                \
      bf16x8 tv;                                                                  \
      _Pragma("unroll")                                                           \
      for (int j = 0; j < 8; ++j) tv[j] = vb[(size_t)((KT) * 64 + w * 8 + j) * D3 + lane]; \
      *(bf16x8*)&Vbuf[(BUF) * 4096 + lane * 64 + ((w ^ (lane & 7)) << 3)] = tv;   \
    }

  ATTN_STAGE(0, 0);

  f32x16 o0 = 0.0f, o1 = 0.0f;
  float m = -INFINITY, l = 0.0f;

  for (int kt = 0; kt < 8; ++kt) {
    __syncthreads();
    if (kt < 7) ATTN_STAGE(kt + 1, (kt + 1) & 1);

    const bf16_t* Kb = Kbuf + (kt & 1) * 4096;
    const bf16_t* Vb = Vbuf + (kt & 1) * 4096;

    f32x16 st0 = 0.0f, st1 = 0.0f;
    #pragma unroll
    for (int ks = 0; ks < 4; ++ks) {
      const int ch = (ks * 2 + hiL) ^ (l31 & 7);
      bf16x8 kf0 = *(const bf16x8*)&Kb[l31 * 64 + ch * 8];
      bf16x8 kf1 = *(const bf16x8*)&Kb[(32 + l31) * 64 + ch * 8];
      st0 = __builtin_amdgcn_mfma_f32_32x32x16_bf16(kf0, qreg[ks], st0, 0, 0, 0);
      st1 = __builtin_amdgcn_mfma_f32_32x32x16_bf16(kf1, qreg[ks], st1, 0, 0, 0);
    }

    float tm = fmaxf(st0[0], st1[0]);
    #pragma unroll
    for (int i = 1; i < 16; ++i) tm = fmaxf(tm, fmaxf(st0[i], st1[i]));
    tm = fmaxf(tm, __shfl_xor(tm, 32));
    const float mnew = fmaxf(m, tm);
    const float al = __expf(m - mnew);
    #pragma unroll
    for (int i = 0; i < 16; ++i) st0[i] = __expf(st0[i] - mnew);
    #pragma unroll
    for (int i = 0; i < 16; ++i) st1[i] = __expf(st1[i] - mnew);
    float ps = 0.0f;
    #pragma unroll
    for (int i = 0; i < 16; ++i) ps += st0[i] + st1[i];
    ps += __shfl_xor(ps, 32);
    l = l * al + ps;
    m = mnew;
    #pragma unroll
    for (int i = 0; i < 16; ++i) { o0[i] *= al; o1[i] *= al; }

    #pragma unroll
    for (int g = 0; g < 2; ++g) {
      unsigned u0, u1, u2, u3, u4, u5, u6, u7;
      if (g == 0) {
        u0 = pkbf(st0[0], st0[1]);   u1 = pkbf(st0[2], st0[3]);
        u2 = pkbf(st0[4], st0[5]);   u3 = pkbf(st0[6], st0[7]);
        u4 = pkbf(st0[8], st0[9]);   u5 = pkbf(st0[10], st0[11]);
        u6 = pkbf(st0[12], st0[13]); u7 = pkbf(st0[14], st0[15]);
      } else {
        u0 = pkbf(st1[0], st1[1]);   u1 = pkbf(st1[2], st1[3]);
        u2 = pkbf(st1[4], st1[5]);   u3 = pkbf(st1[6], st1[7]);
        u4 = pkbf(st1[8], st1[9]);   u5 = pkbf(st1[10], st1[11]);
        u6 = pkbf(st1[12], st1[13]); u7 = pkbf(st1[14], st1[15]);
      }
      #pragma unroll
      for (int ks2 = 0; ks2 < 2; ++ks2) {
        const unsigned a0 = ks2 ? u4 : u0, a1 = ks2 ? u5 : u1;
        const unsigned a2 = ks2 ? u6 : u2, a3 = ks2 ? u7 : u3;
        const unsigned own0 = hiL ? a2 : a0, own1 = hiL ? a3 : a1;
        const unsigned snd0 = hiL ? a0 : a2, snd1 = hiL ? a1 : a3;
        const unsigned rcv0 = (unsigned)__shfl_xor((int)snd0, 32);
        const unsigned rcv1 = (unsigned)__shfl_xor((int)snd1, 32);
        u32x4 fw;
        fw[0] = hiL ? rcv0 : own0;
        fw[1] = hiL ? rcv1 : own1;
        fw[2] = hiL ? own0 : rcv0;
        fw[3] = hiL ? own1 : rcv1;
        const bf16x8 pa = __builtin_bit_cast(bf16x8, fw);
        const int chv = (g * 4 + ks2 * 2 + hiL) ^ (l31 & 7);
        bf16x8 vf0 = *(const bf16x8*)&Vb[l31 * 64 + chv * 8];
        bf16x8 vf1 = *(const bf16x8*)&Vb[(32 + l31) * 64 + chv * 8];
        o0 = __builtin_amdgcn_mfma_f32_32x32x16_bf16(vf0, pa, o0, 0, 0, 0);
        o1 = __builtin_amdgcn_mfma_f32_32x32x16_bf16(vf1, pa, o1, 0, 0, 0);
      }
    }
  }

  __syncthreads();
  const float rl = 1.0f / l;
  bf16_t* Ob = smem;
  #pragma unroll
  for (int reg = 0; reg < 16; ++reg) {
    const int drow = (reg & 3) + 8 * (reg >> 2) + 4 * hiL;
    Ob[(w * 32 + l31) * 72 + drow]      = (bf16_t)(o0[reg] * rl);
    Ob[(w * 32 + l31) * 72 + 32 + drow] = (bf16_t)(o1[reg] * rl);
  }
  __syncthreads();
  const int qrow = tid >> 1, half = tid & 1;
  bf16_t* yp = y + (size_t)(bb * TT + qt * 256 + qrow) * DM + hh * 64 + half * 32;
  const bf16_t* obp = &Ob[qrow * 72 + half * 32];
  *(bf16x8*)(yp)      = *(const bf16x8*)(obp);
  *(bf16x8*)(yp + 8)  = *(const bf16x8*)(obp + 8);
  *(bf16x8*)(yp + 16) = *(const bf16x8*)(obp + 16);
  *(bf16x8*)(yp + 24) = *(const bf16x8*)(obp + 24);
  #undef ATTN_STAGE
}

// ---------------- final LN (CLS) + dense + tanh -> pooled (MERGE: + proj partials) ----------------
template <int MERGE>
__global__ __launch_bounds__(256) void pooled_kernel(const float* __restrict__ x,
                                                     const float* __restrict__ pa,
                                                     const float* __restrict__ lnw,
                                                     const float* __restrict__ lnb,
                                                     const float* __restrict__ dw,
                                                     const float* __restrict__ db,
                                                     float* __restrict__ pooled) {
  const int bb = blockIdx.y, tid = threadIdx.x;
  const int lane = tid & 63, wv = tid >> 6;
  const size_t rb = (size_t)(bb * TT) * DM;
  const float* xr = x + rb;
  float v0 = xr[tid], v1 = xr[tid + 256], v2 = xr[tid + 512];
  if (MERGE) {
    const float* p0 = pa + rb;
    const float* p1 = pa + (size_t)MR * DM + rb;
    v0 += p0[tid]       + p1[tid];
    v1 += p0[tid + 256] + p1[tid + 256];
    v2 += p0[tid + 512] + p1[tid + 512];
  }
  __shared__ float red[8];
  __shared__ float lx[DM];
  float s = v0 + v1 + v2;
  #pragma unroll
  for (int off = 32; off > 0; off >>= 1) s += __shfl_down(s, off);
  if (lane == 0) red[wv] = s;
  __syncthreads();
  const float mean = (red[0] + red[1] + red[2] + red[3]) * (1.0f / DM);
  const float d0 = v0 - mean, d1 = v1 - mean, d2 = v2 - mean;
  float q = d0 * d0 + d1 * d1 + d2 * d2;
  #pragma unroll
  for (int off = 32; off > 0; off >>= 1) q += __shfl_down(q, off);
  __syncthreads();
  if (lane == 0) red[wv] = q;
  __syncthreads();
  const float var = (red[0] + red[1] + red[2] + red[3]) * (1.0f / DM);
  const float rs = rsqrtf(var + 1e-5f);

  lx[tid]       = d0 * rs * lnw[tid] + lnb[tid];
  lx[tid + 256] = d1 * rs * lnw[tid + 256] + lnb[tid + 256];
  lx[tid + 512] = d2 * rs * lnw[tid + 512] + lnb[tid + 512];
  __syncthreads();

  const int j = blockIdx.x * 64 + (tid >> 2), sl = tid & 3;
  const int k0 = sl * 192;
  float acc = 0.0f;
  #pragma unroll 4
  for (int k = k0; k < k0 + 192; ++k) acc += lx[k] * dw[(size_t)k * DM + j];
  acc += __shfl_xor(acc, 1);
  acc += __shfl_xor(acc, 2);
  if (sl == 0) pooled[bb * DM + j] = tanhf(acc + db[j]);
}

// ---------------- logits ----------------
__global__ void logits_kernel(const float* __restrict__ pooled,
                              const float* __restrict__ hw,
                              const float* __restrict__ hb,
                              float* __restrict__ out) {
  const int tid = threadIdx.x;
  if (tid < 32) {
    const int bb = tid >> 1, c = tid & 1;
    float acc = hb[c];
    for (int k = 0; k < DM; ++k) acc += pooled[bb * DM + k] * hw[k * 2 + c];
    out[bb * 2 + c] = acc;
  }
}

extern "C" void kernel_launch(void* const* d_in, const int* in_sizes, int n_in,
                              void* d_out, int out_size, void* d_ws, size_t ws_size,
                              hipStream_t stream) {
  const int*   ids   = (const int*)d_in[0];
  const float* wte   = (const float*)d_in[3];
  const float* wpe   = (const float*)d_in[4];
  const float* ln1w  = (const float*)d_in[5];
  const float* ln1b  = (const float*)d_in[6];
  const float* wqkv  = (const float*)d_in[7];
  const float* bqkv  = (const float*)d_in[8];
  const float* wo    = (const float*)d_in[9];
  const float* bo    = (const float*)d_in[10];
  const float* ln2w  = (const float*)d_in[11];
  const float* ln2b  = (const float*)d_in[12];
  const float* wfc   = (const float*)d_in[13];
  const float* bfc   = (const float*)d_in[14];
  const float* wproj = (const float*)d_in[15];
  const float* bproj = (const float*)d_in[16];
  const float* lnfw  = (const float*)d_in[17];
  const float* lnfb  = (const float*)d_in[18];
  const float* dw    = (const float*)d_in[19];
  const float* db    = (const float*)d_in[20];
  const float* hw    = (const float*)d_in[21];
  const float* hb    = (const float*)d_in[22];
  float* out = (float*)d_out;

  const size_t NEED_FULLW = 308330496ULL;                 // base + 12-layer weights
  const size_t NEED_SLAB  = NEED_FULLW + 50331648ULL;     // + proj partial slab
  const int mode = ws_size >= NEED_SLAB ? 2 : (ws_size >= NEED_FULLW ? 1 : 0);
  const bool full = mode >= 1;
  const bool slab = mode == 2;

  char* ws = (char*)d_ws;
  size_t off = 0;
  auto alloc = [&](size_t bytes) -> void* {
    void* p = ws + off;
    off += (bytes + 255) & ~(size_t)255;
    return p;
  };
  float*  x      = (float*)alloc((size_t)MR * DM * 4);
  bf16_t* h      = (bf16_t*)alloc((size_t)MR * DM * 2);
  bf16_t* qkvb   = (bf16_t*)alloc((size_t)MR * D3 * 2);
  bf16_t* yb     = (bf16_t*)alloc((size_t)MR * DM * 2);
  bf16_t* ub     = (bf16_t*)alloc((size_t)MR * D4 * 2);
  float*  pooled = (float*)alloc((size_t)NB * DM * 4);
  const size_t wmul = full ? NL : 1;
  bf16_t* wqkvT  = (bf16_t*)alloc((size_t)D3 * DM * 2 * wmul);
  bf16_t* woT    = (bf16_t*)alloc((size_t)DM * DM * 2 * wmul);
  bf16_t* wfcT   = (bf16_t*)alloc((size_t)D4 * DM * 2 * wmul);
  bf16_t* wprojT = (bf16_t*)alloc((size_t)DM * D4 * 2 * wmul);
  float*  slabP  = slab ? (float*)alloc((size_t)2 * MR * DM * 4) : nullptr;
  float*  slabW  = (float*)ub;   // wo partials: exact 50.3MB fit, disjoint lifetime vs ub

  embed_kernel<<<MR / 4, 256, 0, stream>>>(ids, wte, wpe, x);

  if (full) {
    transpose_all<<<dim3(864, 1, NL), 256, 0, stream>>>(
        wqkv, wo, wfc, wproj, wqkvT, woT, wfcT, wprojT, 0, 0);
  }

  for (int l = 0; l < NL; ++l) {
    if (!full) {
      transpose_all<<<dim3(864, 1, 1), 256, 0, stream>>>(
          wqkv, wo, wfc, wproj, wqkvT, woT, wfcT, wprojT, l, 1);
    }
    bf16_t* qkvT_l = wqkvT + (full ? (size_t)l * D3 * DM : 0);
    bf16_t* woT_l  = woT   + (full ? (size_t)l * DM * DM : 0);
    bf16_t* fcT_l  = wfcT  + (full ? (size_t)l * D4 * DM : 0);
    bf16_t* prT_l  = wprojT+ (full ? (size_t)l * DM * D4 : 0);

    // ln1: merge previous layer's proj partials (slab mode, l>0)
    if (slab && l > 0)
      ln_kernel<1><<<MR / 4, 256, 0, stream>>>(x, slabP, ln1w + l * DM, ln1b + l * DM, h);
    else
      ln_kernel<0><<<MR / 4, 256, 0, stream>>>(x, nullptr, ln1w + l * DM, ln1b + l * DM, h);

    gemm8<0, 1, 1><<<dim3(D3 / 256, MR / 256, 1), 512, 0, stream>>>(
        h, qkvT_l, bqkv + (size_t)l * D3, qkvb, nullptr, D3, DM, DM, D3 / 256);
    attn_kernel<<<dim3(TT / 256, NH, NB), 512, 0, stream>>>(qkvb, yb);

    if (slab) {
      gemm8<2, 2, 0><<<dim3(DM / 256, MR / 256, 2), 512, 0, stream>>>(
          yb, woT_l, bo + (size_t)l * DM, nullptr, slabW, DM, DM / 2, DM, DM / 256);
      ln_kernel<1><<<MR / 4, 256, 0, stream>>>(x, slabW, ln2w + l * DM, ln2b + l * DM, h);
    } else {
      gemm8<2, 2, 1><<<dim3(DM / 256, MR / 256, 2), 512, 0, stream>>>(
          yb, woT_l, bo + (size_t)l * DM, nullptr, x, DM, DM / 2, DM, DM / 256);
      ln_kernel<0><<<MR / 4, 256, 0, stream>>>(x, nullptr, ln2w + l * DM, ln2b + l * DM, h);
    }

    gemm8<1, 1, 1><<<dim3(D4 / 256, MR / 256, 1), 512, 0, stream>>>(
        h, fcT_l, bfc + (size_t)l * D4, ub, nullptr, D4, DM, DM, D4 / 256);

    if (slab) {
      gemm8<2, 2, 0><<<dim3(DM / 256, MR / 256, 2), 512, 0, stream>>>(
          ub, prT_l, bproj + (size_t)l * DM, nullptr, slabP, DM, D4 / 2, D4, DM / 256);
    } else {
      gemm8<2, 2, 1><<<dim3(DM / 256, MR / 256, 2), 512, 0, stream>>>(
          ub, prT_l, bproj + (size_t)l * DM, nullptr, x, DM, D4 / 2, D4, DM / 256);
    }
  }

  if (slab)
    pooled_kernel<1><<<dim3(12, NB), 256, 0, stream>>>(x, slabP, lnfw, lnfb, dw, db, pooled);
  else
    pooled_kernel<0><<<dim3(12, NB), 256, 0, stream>>>(x, nullptr, lnfw, lnfb, dw, db, pooled);
  logits_kernel<<<1, 64, 0, stream>>>(pooled, hw, hb, out);
}

// Round 9
// 3114.363 us; speedup vs baseline: 1.3377x; 1.0311x over previous
//
#include <hip/hip_runtime.h>
#include <hip/hip_bf16.h>
#include <math.h>

// Problem constants
#define NL 12
#define NH 12
#define DM 768
#define DH 64
#define TT 512
#define NB 16
#define MR (NB*TT)      // 8192 rows
#define D3 (3*DM)       // 2304
#define D4 (4*DM)       // 3072

typedef __bf16 bf16_t;
typedef __attribute__((ext_vector_type(8))) __bf16 bf16x8;
typedef __attribute__((ext_vector_type(4))) __bf16 bf16x4;
typedef __attribute__((ext_vector_type(4))) float f32x4;
typedef __attribute__((ext_vector_type(16))) float f32x16;
typedef __attribute__((ext_vector_type(4))) unsigned int u32x4;

__device__ __forceinline__ void gload_lds16(const void* g, void* l) {
  __builtin_amdgcn_global_load_lds(
      (const __attribute__((address_space(1))) unsigned int*)g,
      (__attribute__((address_space(3))) unsigned int*)l,
      16, 0, 0);
}

__device__ __forceinline__ unsigned pkbf(float a, float b) {
  unsigned short ua = __builtin_bit_cast(unsigned short, (bf16_t)a);
  unsigned short ub = __builtin_bit_cast(unsigned short, (bf16_t)b);
  return (unsigned)ua | ((unsigned)ub << 16);
}

// ---------------- batched weight transpose + f32->bf16 into BLOCKED layout ----------------
// 64k x 128n tiles. Output [ktile][nb][row 0..255][chunk p][8 bf16]; stored chunk p
// holds original k-chunk (p ^ (row&7)). XOR on LDS READ side -> global writes
// fully coalesced. f32 loads are NON-TEMPORAL (read exactly once; keep L3 for
// the bf16 tiles the GEMMs re-read).
__global__ __launch_bounds__(256) void transpose_all(
    const float* __restrict__ wqkv, const float* __restrict__ wo,
    const float* __restrict__ wfc, const float* __restrict__ wproj,
    bf16_t* __restrict__ qkvT, bf16_t* __restrict__ woT,
    bf16_t* __restrict__ fcT, bf16_t* __restrict__ projT,
    int l0, int per_layer_out) {
  const int lay = l0 + blockIdx.z;
  int bid = blockIdx.x;
  const float* in; bf16_t* out; int N;
  if (bid < 216) {
    in = wqkv + (size_t)lay * DM * D3;
    out = qkvT + (per_layer_out ? 0 : (size_t)lay * D3 * DM);
    N = D3;
  } else if (bid < 288) {
    bid -= 216;
    in = wo + (size_t)lay * DM * DM;
    out = woT + (per_layer_out ? 0 : (size_t)lay * DM * DM);
    N = DM;
  } else if (bid < 576) {
    bid -= 288;
    in = wfc + (size_t)lay * DM * D4;
    out = fcT + (per_layer_out ? 0 : (size_t)lay * D4 * DM);
    N = D4;
  } else {
    bid -= 576;
    in = wproj + (size_t)lay * D4 * DM;
    out = projT + (per_layer_out ? 0 : (size_t)lay * DM * D4);
    N = DM;
  }
  const int nx = N >> 7;
  const int n0 = (bid % nx) * 128, k0 = (bid / nx) * 64;
  __shared__ float tile[64][128];   // 32 KB
  const int t = threadIdx.x;
  const int rr = t >> 5, c4 = (t & 31) * 4;
  #pragma unroll
  for (int it = 0; it < 8; ++it) {
    const int row = rr + it * 8;
    f32x4 v = __builtin_nontemporal_load((const f32x4*)&in[(size_t)(k0 + row) * N + n0 + c4]);
    *(f32x4*)&tile[row][c4] = v;
  }
  __syncthreads();
  const int n = t >> 1, kh = t & 1;
  const int rg = (n0 & 255) + n;
  const int nb = n0 >> 8;
  const int nbN = N >> 8;
  const int x = rg & 7;
  bf16_t* base = out + (((size_t)(k0 >> 6) * nbN + nb) * 256 + rg) * 64 + kh * 32;
  #pragma unroll
  for (int p4 = 0; p4 < 4; ++p4) {
    const int c = (kh * 4 + p4) ^ x;      // source k-chunk for stored position
    bf16x8 o;
    #pragma unroll
    for (int j = 0; j < 8; ++j) o[j] = (bf16_t)tile[c * 8 + j][n];
    *(bf16x8*)(base + (p4 << 3)) = o;
  }
}

// ---------------- embedding: wave-per-row, float4 ----------------
__global__ __launch_bounds__(256) void embed_kernel(const int* __restrict__ ids,
                                                    const float* __restrict__ wte,
                                                    const float* __restrict__ wpe,
                                                    float* __restrict__ x) {
  const int lane = threadIdx.x & 63, wv = threadIdx.x >> 6;
  const int row = blockIdx.x * 4 + wv;
  const int t = row & (TT - 1);
  const int id = ids[row];
  const int c = lane * 4;
  const float* wt = wte + (size_t)id * DM;
  const float* wp = wpe + (size_t)t * DM;
  float* xr = x + (size_t)row * DM;
  #pragma unroll
  for (int i = 0; i < 3; ++i) {
    const int cc = c + i * 256;
    float4 a = *(const float4*)&wt[cc];
    float4 b = *(const float4*)&wp[cc];
    a.x += b.x; a.y += b.y; a.z += b.z; a.w += b.w;
    *(float4*)&xr[cc] = a;
  }
}

// ---------------- LayerNorm, one WAVE per row; MERGE: x += pa_z0 + pa_z1 (bf16 slabs) ----------------
template <int MERGE>
__global__ __launch_bounds__(256) void ln_kernel(float* __restrict__ x,
                                                 const bf16_t* __restrict__ pa,
                                                 const float* __restrict__ w,
                                                 const float* __restrict__ b,
                                                 bf16_t* __restrict__ out) {
  const int lane = threadIdx.x & 63, wv = threadIdx.x >> 6;
  const int row = blockIdx.x * 4 + wv;
  float* xr = x + (size_t)row * DM;
  const int c = lane * 4;
  float4 v0 = *(const float4*)&xr[c];
  float4 v1 = *(const float4*)&xr[c + 256];
  float4 v2 = *(const float4*)&xr[c + 512];
  if (MERGE) {
    const bf16_t* p0 = pa + (size_t)row * DM;
    const bf16_t* p1 = pa + (size_t)MR * DM + (size_t)row * DM;
    #pragma unroll
    for (int i = 0; i < 3; ++i) {
      const int cc = c + i * 256;
      bf16x4 a = *(const bf16x4*)&p0[cc];
      bf16x4 bb = *(const bf16x4*)&p1[cc];
      float4& v = i == 0 ? v0 : (i == 1 ? v1 : v2);
      v.x += (float)a[0] + (float)bb[0];
      v.y += (float)a[1] + (float)bb[1];
      v.z += (float)a[2] + (float)bb[2];
      v.w += (float)a[3] + (float)bb[3];
      *(float4*)&xr[cc] = v;
    }
  }
  float s = v0.x + v0.y + v0.z + v0.w + v1.x + v1.y + v1.z + v1.w
          + v2.x + v2.y + v2.z + v2.w;
  #pragma unroll
  for (int off = 32; off > 0; off >>= 1) s += __shfl_xor(s, off);
  const float mean = s * (1.0f / DM);
  float q = 0.0f;
  q += (v0.x-mean)*(v0.x-mean) + (v0.y-mean)*(v0.y-mean) + (v0.z-mean)*(v0.z-mean) + (v0.w-mean)*(v0.w-mean);
  q += (v1.x-mean)*(v1.x-mean) + (v1.y-mean)*(v1.y-mean) + (v1.z-mean)*(v1.z-mean) + (v1.w-mean)*(v1.w-mean);
  q += (v2.x-mean)*(v2.x-mean) + (v2.y-mean)*(v2.y-mean) + (v2.z-mean)*(v2.z-mean) + (v2.w-mean)*(v2.w-mean);
  #pragma unroll
  for (int off = 32; off > 0; off >>= 1) q += __shfl_xor(q, off);
  const float rs = rsqrtf(q * (1.0f / DM) + 1e-5f);
  bf16_t* o = out + (size_t)row * DM;
  #pragma unroll
  for (int i = 0; i < 3; ++i) {
    const int cc = c + i * 256;
    float4 vv = i == 0 ? v0 : (i == 1 ? v1 : v2);
    float4 ww = *(const float4*)&w[cc];
    float4 bb = *(const float4*)&b[cc];
    bf16x4 ob;
    ob[0] = (bf16_t)((vv.x - mean) * rs * ww.x + bb.x);
    ob[1] = (bf16_t)((vv.y - mean) * rs * ww.y + bb.y);
    ob[2] = (bf16_t)((vv.z - mean) * rs * ww.z + bb.z);
    ob[3] = (bf16_t)((vv.w - mean) * rs * ww.w + bb.w);
    *(bf16x4*)&o[cc] = ob;
  }
}

// =====================================================================
// 256x256 8-phase GEMM (T1+T2+T3/T4+T5). B pre-swizzled+blocked [t][nb][256][8ch].
// SPLITK>1: blockIdx.z covers k-range. EPI2: ATOM=1 -> f32 atomicAdd into resid;
// ATOM=0 -> bf16 partial store into outb[z*MR*Ndim + ...] (merged by LN).
// =====================================================================
#define OFF(S, MAT, H) (((((S)*2 + (MAT))*2) + (H)) * 8192)

#define STAGE(S, MAT, H, T) do {                                                \
    const int _r0 = tid >> 3, _r1 = _r0 + 64, _c = tid & 7;                     \
    if ((MAT) == 0) {                                                           \
      const bf16_t* _g0 = A + (size_t)(m0 + ((_r0 >> 6) << 7) + (H)*64 + (_r0 & 63)) * Kstride \
              + (T)*64 + ((_c ^ (_r0 & 7)) << 3);                               \
      const bf16_t* _g1 = A + (size_t)(m0 + ((_r1 >> 6) << 7) + (H)*64 + (_r1 & 63)) * Kstride \
              + (T)*64 + ((_c ^ (_r1 & 7)) << 3);                               \
      gload_lds16(_g0, &lds[OFF(S, 0, H) + (w << 9)]);                          \
      gload_lds16(_g1, &lds[OFF(S, 0, H) + 4096 + (w << 9)]);                   \
    } else {                                                                    \
      const int _gr0 = ((_r0 >> 5) << 6) + (H)*32 + (_r0 & 31);                 \
      const int _gr1 = ((_r1 >> 5) << 6) + (H)*32 + (_r1 & 31);                 \
      const bf16_t* _bb = BTB + (((size_t)(T) * nbN + nb) << 14);               \
      gload_lds16(_bb + (_gr0 << 6) + (_c << 3), &lds[OFF(S, 1, H) + (w << 9)]);        \
      gload_lds16(_bb + (_gr1 << 6) + (_c << 3), &lds[OFF(S, 1, H) + 4096 + (w << 9)]); \
    }                                                                           \
  } while (0)

#define RD_A(S, MH) do {                                                        \
    _Pragma("unroll") for (int _mf = 0; _mf < 4; ++_mf) {                       \
      const int _lr = wr * 64 + _mf * 16 + l15;                                 \
      const int _x = _lr & 7;                                                   \
      af[_mf][0] = *(const bf16x8*)&lds[OFF(S,0,MH) + _lr*64 + ((l4 ^ _x) << 3)];        \
      af[_mf][1] = *(const bf16x8*)&lds[OFF(S,0,MH) + _lr*64 + (((4+l4) ^ _x) << 3)];    \
    } } while (0)

#define RD_B(S, NH) do {                                                        \
    _Pragma("unroll") for (int _nf = 0; _nf < 2; ++_nf) {                       \
      const int _lr = wc * 32 + _nf * 16 + l15;                                 \
      const int _x = _lr & 7;                                                   \
      bfr[_nf][0] = *(const bf16x8*)&lds[OFF(S,1,NH) + _lr*64 + ((l4 ^ _x) << 3)];       \
      bfr[_nf][1] = *(const bf16x8*)&lds[OFF(S,1,NH) + _lr*64 + (((4+l4) ^ _x) << 3)];   \
    } } while (0)

#define MM(MH, NH) do {                                                         \
    __builtin_amdgcn_s_setprio(1);                                              \
    _Pragma("unroll") for (int _ks = 0; _ks < 2; ++_ks)                         \
      _Pragma("unroll") for (int _mf = 0; _mf < 4; ++_mf)                       \
        _Pragma("unroll") for (int _nf = 0; _nf < 2; ++_nf)                     \
          acc[(MH)*4+_mf][(NH)*2+_nf] = __builtin_amdgcn_mfma_f32_16x16x32_bf16(\
              af[_mf][_ks], bfr[_nf][_ks], acc[(MH)*4+_mf][(NH)*2+_nf], 0,0,0); \
    __builtin_amdgcn_s_setprio(0);                                              \
  } while (0)

#define BAR()   __builtin_amdgcn_s_barrier()
#define LGKM0() asm volatile("s_waitcnt lgkmcnt(0)" ::: "memory")
#define LGKM8() asm volatile("s_waitcnt lgkmcnt(8)" ::: "memory")
#define VM6()   asm volatile("s_waitcnt vmcnt(6)" ::: "memory")

// EPI: 0 = +bias -> bf16 ; 1 = +bias, tanh-approx GELU -> bf16 ; 2 = resid (see above)
template <int EPI, int SPLITK, int ATOM>
__global__ __launch_bounds__(512, 2) void gemm8(const bf16_t* __restrict__ A,
                                                const bf16_t* __restrict__ BTB,
                                                const float* __restrict__ bias,
                                                bf16_t* __restrict__ outb,
                                                float* __restrict__ resid,
                                                int Ndim, int Kdim, int Kstride, int nbN) {
  __shared__ bf16_t lds[65536];   // 128 KB
  const int tid = threadIdx.x, lane = tid & 63, w = tid >> 6;
  const int wr = w >> 2, wc = w & 3;
  const int l15 = lane & 15, l4 = lane >> 4;
  const int zz = (SPLITK > 1) ? blockIdx.z : 0;
  A += (size_t)zz * Kdim;
  BTB += ((size_t)zz * (Kdim >> 6) * nbN) << 14;

  // T1: bijective XCD-aware tile swizzle (m204). All grids here are %8==0.
  const unsigned nwg = gridDim.x * gridDim.y;
  const unsigned orig = blockIdx.y * gridDim.x + blockIdx.x;
  const unsigned q8 = nwg >> 3;
  const unsigned wg = (orig & 7) * q8 + (orig >> 3);
  const int nb = (int)(wg % gridDim.x);
  const int m0 = (int)(wg / gridDim.x) * 256, n0 = nb * 256;
  const int nT = Kdim >> 6, nIter = Kdim >> 7;

  f32x4 acc[8][4] = {};
  bf16x8 af[4][2], bfr[2][2];

  STAGE(0, 0, 0, 0); STAGE(0, 1, 0, 0); STAGE(0, 0, 1, 0); STAGE(0, 1, 1, 0);
  asm volatile("s_waitcnt vmcnt(4)" ::: "memory");
  STAGE(1, 0, 0, 1); STAGE(1, 1, 1, 1); STAGE(1, 0, 1, 1);
  asm volatile("s_waitcnt vmcnt(6)" ::: "memory");
  BAR();

  for (int it = 0; it < nIter; ++it) {
    const int t1 = 2 * it + 1;
    int ts0 = 2 * it + 2; if (ts0 >= nT) ts0 -= nT;
    int ts1 = 2 * it + 3; if (ts1 >= nT) ts1 -= nT;
    RD_A(0, 0); RD_B(0, 0); STAGE(1, 1, 0, t1);
    LGKM8(); BAR(); LGKM0(); MM(0, 0); BAR();
    RD_B(0, 1); STAGE(0, 0, 0, ts0);
    BAR(); LGKM0(); MM(0, 1); BAR();
    RD_A(0, 1); STAGE(0, 1, 1, ts0);
    BAR(); LGKM0(); MM(1, 1); BAR();
    RD_B(0, 0); STAGE(0, 0, 1, ts0);
    BAR(); LGKM0(); MM(1, 0); VM6(); BAR();
    RD_A(1, 0); RD_B(1, 0); STAGE(0, 1, 0, ts0);
    LGKM8(); BAR(); LGKM0(); MM(0, 0); BAR();
    RD_B(1, 1); STAGE(1, 0, 0, ts1);
    BAR(); LGKM0(); MM(0, 1); BAR();
    RD_A(1, 1); STAGE(1, 1, 1, ts1);
    BAR(); LGKM0(); MM(1, 1); BAR();
    RD_B(1, 0); STAGE(1, 0, 1, ts1);
    BAR(); LGKM0(); MM(1, 0); VM6(); BAR();
  }

  // epilogue
  #pragma unroll
  for (int mf = 0; mf < 8; ++mf) {
    #pragma unroll
    for (int nf = 0; nf < 4; ++nf) {
      const int col = n0 + wc * 64 + nf * 16 + l15;
      const float bv = (SPLITK == 1 || zz == 0) ? bias[col] : 0.0f;
      #pragma unroll
      for (int r = 0; r < 4; ++r) {
        const int row = m0 + wr * 128 + mf * 16 + l4 * 4 + r;
        float v = acc[mf][nf][r] + bv;
        if (EPI == 1) {
          const float z2 = 1.5957692f * v + 0.07135481f * v * v * v;
          v = v / (1.0f + __expf(-z2));
        }
        if (EPI == 2) {
          if (SPLITK > 1 && ATOM == 0) {
            outb[(size_t)zz * MR * Ndim + (size_t)row * Ndim + col] = (bf16_t)v;
          } else if (SPLITK > 1) {
            unsafeAtomicAdd(&resid[(size_t)row * Ndim + col], v);
          } else {
            resid[(size_t)row * Ndim + col] += v;
          }
        } else {
          outb[(size_t)row * Ndim + col] = (bf16_t)v;
        }
      }
    }
  }
}

// ---------------- fused flash attention (unchanged) ----------------
__global__ __launch_bounds__(512, 4) void attn_kernel(const bf16_t* __restrict__ qkv,
                                                      bf16_t* __restrict__ y) {
  const int qt = blockIdx.x, hh = blockIdx.y, bb = blockIdx.z;
  const int tid = threadIdx.x, lane = tid & 63, w = tid >> 6;
  const int l31 = lane & 31, hiL = lane >> 5;

  __shared__ bf16_t smem[18432];
  bf16_t* Kbuf = smem;
  bf16_t* Vbuf = smem + 8192;

  const bf16_t* kb = qkv + (size_t)(bb * TT) * D3 + DM + hh * 64;
  const bf16_t* vb = qkv + (size_t)(bb * TT) * D3 + 2 * DM + hh * 64;

  const bf16_t* qptr = qkv + (size_t)(bb * TT + qt * 256 + w * 32 + l31) * D3 + hh * 64 + hiL * 8;
  bf16x8 qreg[4];
  #pragma unroll
  for (int ks = 0; ks < 4; ++ks) {
    bf16x8 v = *(const bf16x8*)(qptr + ks * 16);
    #pragma unroll
    for (int j = 0; j < 8; ++j) qreg[ks][j] = (bf16_t)((float)v[j] * 0.125f);
  }

  const int sr = tid >> 3, sc = tid & 7;
  #define ATTN_STAGE(KT, BUF)                                                     \
    {                                                                             \
      gload_lds16(kb + (size_t)((KT) * 64 + sr) * D3 + ((sc ^ (sr & 7)) * 8),     \
                  Kbuf + (BUF) * 4096 + (w << 9));                                \
      bf16x8 tv;                                                                  \
      _Pragma("unroll")                                                           \
      for (int j = 0; j < 8; ++j) tv[j] = vb[(size_t)((KT) * 64 + w * 8 + j) * D3 + lane]; \
      *(bf16x8*)&Vbuf[(BUF) * 4096 + lane * 64 + ((w ^ (lane & 7)) << 3)] = tv;   \
    }

  ATTN_STAGE(0, 0);

  f32x16 o0 = 0.0f, o1 = 0.0f;
  float m = -INFINITY, l = 0.0f;

  for (int kt = 0; kt < 8; ++kt) {
    __syncthreads();
    if (kt < 7) ATTN_STAGE(kt + 1, (kt + 1) & 1);

    const bf16_t* Kb = Kbuf + (kt & 1) * 4096;
    const bf16_t* Vb = Vbuf + (kt & 1) * 4096;

    f32x16 st0 = 0.0f, st1 = 0.0f;
    #pragma unroll
    for (int ks = 0; ks < 4; ++ks) {
      const int ch = (ks * 2 + hiL) ^ (l31 & 7);
      bf16x8 kf0 = *(const bf16x8*)&Kb[l31 * 64 + ch * 8];
      bf16x8 kf1 = *(const bf16x8*)&Kb[(32 + l31) * 64 + ch * 8];
      st0 = __builtin_amdgcn_mfma_f32_32x32x16_bf16(kf0, qreg[ks], st0, 0, 0, 0);
      st1 = __builtin_amdgcn_mfma_f32_32x32x16_bf16(kf1, qreg[ks], st1, 0, 0, 0);
    }

    float tm = fmaxf(st0[0], st1[0]);
    #pragma unroll
    for (int i = 1; i < 16; ++i) tm = fmaxf(tm, fmaxf(st0[i], st1[i]));
    tm = fmaxf(tm, __shfl_xor(tm, 32));
    const float mnew = fmaxf(m, tm);
    const float al = __expf(m - mnew);
    #pragma unroll
    for (int i = 0; i < 16; ++i) st0[i] = __expf(st0[i] - mnew);
    #pragma unroll
    for (int i = 0; i < 16; ++i) st1[i] = __expf(st1[i] - mnew);
    float ps = 0.0f;
    #pragma unroll
    for (int i = 0; i < 16; ++i) ps += st0[i] + st1[i];
    ps += __shfl_xor(ps, 32);
    l = l * al + ps;
    m = mnew;
    #pragma unroll
    for (int i = 0; i < 16; ++i) { o0[i] *= al; o1[i] *= al; }

    #pragma unroll
    for (int g = 0; g < 2; ++g) {
      unsigned u0, u1, u2, u3, u4, u5, u6, u7;
      if (g == 0) {
        u0 = pkbf(st0[0], st0[1]);   u1 = pkbf(st0[2], st0[3]);
        u2 = pkbf(st0[4], st0[5]);   u3 = pkbf(st0[6], st0[7]);
        u4 = pkbf(st0[8], st0[9]);   u5 = pkbf(st0[10], st0[11]);
        u6 = pkbf(st0[12], st0[13]); u7 = pkbf(st0[14], st0[15]);
      } else {
        u0 = pkbf(st1[0], st1[1]);   u1 = pkbf(st1[2], st1[3]);
        u2 = pkbf(st1[4], st1[5]);   u3 = pkbf(st1[6], st1[7]);
        u4 = pkbf(st1[8], st1[9]);   u5 = pkbf(st1[10], st1[11]);
        u6 = pkbf(st1[12], st1[13]); u7 = pkbf(st1[14], st1[15]);
      }
      #pragma unroll
      for (int ks2 = 0; ks2 < 2; ++ks2) {
        const unsigned a0 = ks2 ? u4 : u0, a1 = ks2 ? u5 : u1;
        const unsigned a2 = ks2 ? u6 : u2, a3 = ks2 ? u7 : u3;
        const unsigned own0 = hiL ? a2 : a0, own1 = hiL ? a3 : a1;
        const unsigned snd0 = hiL ? a0 : a2, snd1 = hiL ? a1 : a3;
        const unsigned rcv0 = (unsigned)__shfl_xor((int)snd0, 32);
        const unsigned rcv1 = (unsigned)__shfl_xor((int)snd1, 32);
        u32x4 fw;
        fw[0] = hiL ? rcv0 : own0;
        fw[1] = hiL ? rcv1 : own1;
        fw[2] = hiL ? own0 : rcv0;
        fw[3] = hiL ? own1 : rcv1;
        const bf16x8 pa = __builtin_bit_cast(bf16x8, fw);
        const int chv = (g * 4 + ks2 * 2 + hiL) ^ (l31 & 7);
        bf16x8 vf0 = *(const bf16x8*)&Vb[l31 * 64 + chv * 8];
        bf16x8 vf1 = *(const bf16x8*)&Vb[(32 + l31) * 64 + chv * 8];
        o0 = __builtin_amdgcn_mfma_f32_32x32x16_bf16(vf0, pa, o0, 0, 0, 0);
        o1 = __builtin_amdgcn_mfma_f32_32x32x16_bf16(vf1, pa, o1, 0, 0, 0);
      }
    }
  }

  __syncthreads();
  const float rl = 1.0f / l;
  bf16_t* Ob = smem;
  #pragma unroll
  for (int reg = 0; reg < 16; ++reg) {
    const int drow = (reg & 3) + 8 * (reg >> 2) + 4 * hiL;
    Ob[(w * 32 + l31) * 72 + drow]      = (bf16_t)(o0[reg] * rl);
    Ob[(w * 32 + l31) * 72 + 32 + drow] = (bf16_t)(o1[reg] * rl);
  }
  __syncthreads();
  const int qrow = tid >> 1, half = tid & 1;
  bf16_t* yp = y + (size_t)(bb * TT + qt * 256 + qrow) * DM + hh * 64 + half * 32;
  const bf16_t* obp = &Ob[qrow * 72 + half * 32];
  *(bf16x8*)(yp)      = *(const bf16x8*)(obp);
  *(bf16x8*)(yp + 8)  = *(const bf16x8*)(obp + 8);
  *(bf16x8*)(yp + 16) = *(const bf16x8*)(obp + 16);
  *(bf16x8*)(yp + 24) = *(const bf16x8*)(obp + 24);
  #undef ATTN_STAGE
}

// ---------------- final LN (CLS) + dense + tanh -> pooled (MERGE: + bf16 partials) ----------------
template <int MERGE>
__global__ __launch_bounds__(256) void pooled_kernel(const float* __restrict__ x,
                                                     const bf16_t* __restrict__ pa,
                                                     const float* __restrict__ lnw,
                                                     const float* __restrict__ lnb,
                                                     const float* __restrict__ dw,
                                                     const float* __restrict__ db,
                                                     float* __restrict__ pooled) {
  const int bb = blockIdx.y, tid = threadIdx.x;
  const int lane = tid & 63, wv = tid >> 6;
  const size_t rb = (size_t)(bb * TT) * DM;
  const float* xr = x + rb;
  float v0 = xr[tid], v1 = xr[tid + 256], v2 = xr[tid + 512];
  if (MERGE) {
    const bf16_t* p0 = pa + rb;
    const bf16_t* p1 = pa + (size_t)MR * DM + rb;
    v0 += (float)p0[tid]       + (float)p1[tid];
    v1 += (float)p0[tid + 256] + (float)p1[tid + 256];
    v2 += (float)p0[tid + 512] + (float)p1[tid + 512];
  }
  __shared__ float red[8];
  __shared__ float lx[DM];
  float s = v0 + v1 + v2;
  #pragma unroll
  for (int off = 32; off > 0; off >>= 1) s += __shfl_down(s, off);
  if (lane == 0) red[wv] = s;
  __syncthreads();
  const float mean = (red[0] + red[1] + red[2] + red[3]) * (1.0f / DM);
  const float d0 = v0 - mean, d1 = v1 - mean, d2 = v2 - mean;
  float q = d0 * d0 + d1 * d1 + d2 * d2;
  #pragma unroll
  for (int off = 32; off > 0; off >>= 1) q += __shfl_down(q, off);
  __syncthreads();
  if (lane == 0) red[wv] = q;
  __syncthreads();
  const float var = (red[0] + red[1] + red[2] + red[3]) * (1.0f / DM);
  const float rs = rsqrtf(var + 1e-5f);

  lx[tid]       = d0 * rs * lnw[tid] + lnb[tid];
  lx[tid + 256] = d1 * rs * lnw[tid + 256] + lnb[tid + 256];
  lx[tid + 512] = d2 * rs * lnw[tid + 512] + lnb[tid + 512];
  __syncthreads();

  const int j = blockIdx.x * 64 + (tid >> 2), sl = tid & 3;
  const int k0 = sl * 192;
  float acc = 0.0f;
  #pragma unroll 4
  for (int k = k0; k < k0 + 192; ++k) acc += lx[k] * dw[(size_t)k * DM + j];
  acc += __shfl_xor(acc, 1);
  acc += __shfl_xor(acc, 2);
  if (sl == 0) pooled[bb * DM + j] = tanhf(acc + db[j]);
}

// ---------------- logits ----------------
__global__ void logits_kernel(const float* __restrict__ pooled,
                              const float* __restrict__ hw,
                              const float* __restrict__ hb,
                              float* __restrict__ out) {
  const int tid = threadIdx.x;
  if (tid < 32) {
    const int bb = tid >> 1, c = tid & 1;
    float acc = hb[c];
    for (int k = 0; k < DM; ++k) acc += pooled[bb * DM + k] * hw[k * 2 + c];
    out[bb * 2 + c] = acc;
  }
}

extern "C" void kernel_launch(void* const* d_in, const int* in_sizes, int n_in,
                              void* d_out, int out_size, void* d_ws, size_t ws_size,
                              hipStream_t stream) {
  const int*   ids   = (const int*)d_in[0];
  const float* wte   = (const float*)d_in[3];
  const float* wpe   = (const float*)d_in[4];
  const float* ln1w  = (const float*)d_in[5];
  const float* ln1b  = (const float*)d_in[6];
  const float* wqkv  = (const float*)d_in[7];
  const float* bqkv  = (const float*)d_in[8];
  const float* wo    = (const float*)d_in[9];
  const float* bo    = (const float*)d_in[10];
  const float* ln2w  = (const float*)d_in[11];
  const float* ln2b  = (const float*)d_in[12];
  const float* wfc   = (const float*)d_in[13];
  const float* bfc   = (const float*)d_in[14];
  const float* wproj = (const float*)d_in[15];
  const float* bproj = (const float*)d_in[16];
  const float* lnfw  = (const float*)d_in[17];
  const float* lnfb  = (const float*)d_in[18];
  const float* dw    = (const float*)d_in[19];
  const float* db    = (const float*)d_in[20];
  const float* hw    = (const float*)d_in[21];
  const float* hb    = (const float*)d_in[22];
  float* out = (float*)d_out;

  const size_t NEED_FULLW = 308330496ULL;                 // base + 12-layer weights
  const size_t NEED_SLAB  = NEED_FULLW + 25165824ULL;     // + bf16 proj partial slab
  const int mode = ws_size >= NEED_SLAB ? 2 : (ws_size >= NEED_FULLW ? 1 : 0);
  const bool full = mode >= 1;
  const bool slab = mode == 2;

  char* ws = (char*)d_ws;
  size_t off = 0;
  auto alloc = [&](size_t bytes) -> void* {
    void* p = ws + off;
    off += (bytes + 255) & ~(size_t)255;
    return p;
  };
  float*  x      = (float*)alloc((size_t)MR * DM * 4);
  bf16_t* h      = (bf16_t*)alloc((size_t)MR * DM * 2);
  bf16_t* qkvb   = (bf16_t*)alloc((size_t)MR * D3 * 2);
  bf16_t* yb     = (bf16_t*)alloc((size_t)MR * DM * 2);
  bf16_t* ub     = (bf16_t*)alloc((size_t)MR * D4 * 2);
  float*  pooled = (float*)alloc((size_t)NB * DM * 4);
  const size_t wmul = full ? NL : 1;
  bf16_t* wqkvT  = (bf16_t*)alloc((size_t)D3 * DM * 2 * wmul);
  bf16_t* woT    = (bf16_t*)alloc((size_t)DM * DM * 2 * wmul);
  bf16_t* wfcT   = (bf16_t*)alloc((size_t)D4 * DM * 2 * wmul);
  bf16_t* wprojT = (bf16_t*)alloc((size_t)DM * D4 * 2 * wmul);
  bf16_t* slabP  = slab ? (bf16_t*)alloc((size_t)2 * MR * DM * 2) : nullptr;
  bf16_t* slabW  = (bf16_t*)ub;   // wo partials alias ub (25MB of 50MB; disjoint lifetime)

  embed_kernel<<<MR / 4, 256, 0, stream>>>(ids, wte, wpe, x);

  if (full) {
    transpose_all<<<dim3(864, 1, NL), 256, 0, stream>>>(
        wqkv, wo, wfc, wproj, wqkvT, woT, wfcT, wprojT, 0, 0);
  }

  for (int l = 0; l < NL; ++l) {
    if (!full) {
      transpose_all<<<dim3(864, 1, 1), 256, 0, stream>>>(
          wqkv, wo, wfc, wproj, wqkvT, woT, wfcT, wprojT, l, 1);
    }
    bf16_t* qkvT_l = wqkvT + (full ? (size_t)l * D3 * DM : 0);
    bf16_t* woT_l  = woT   + (full ? (size_t)l * DM * DM : 0);
    bf16_t* fcT_l  = wfcT  + (full ? (size_t)l * D4 * DM : 0);
    bf16_t* prT_l  = wprojT+ (full ? (size_t)l * DM * D4 : 0);

    // ln1: merge previous layer's proj partials (slab mode, l>0)
    if (slab && l > 0)
      ln_kernel<1><<<MR / 4, 256, 0, stream>>>(x, slabP, ln1w + l * DM, ln1b + l * DM, h);
    else
      ln_kernel<0><<<MR / 4, 256, 0, stream>>>(x, nullptr, ln1w + l * DM, ln1b + l * DM, h);

    gemm8<0, 1, 1><<<dim3(D3 / 256, MR / 256, 1), 512, 0, stream>>>(
        h, qkvT_l, bqkv + (size_t)l * D3, qkvb, nullptr, D3, DM, DM, D3 / 256);
    attn_kernel<<<dim3(TT / 256, NH, NB), 512, 0, stream>>>(qkvb, yb);

    if (slab) {
      gemm8<2, 2, 0><<<dim3(DM / 256, MR / 256, 2), 512, 0, stream>>>(
          yb, woT_l, bo + (size_t)l * DM, slabW, nullptr, DM, DM / 2, DM, DM / 256);
      ln_kernel<1><<<MR / 4, 256, 0, stream>>>(x, slabW, ln2w + l * DM, ln2b + l * DM, h);
    } else {
      gemm8<2, 2, 1><<<dim3(DM / 256, MR / 256, 2), 512, 0, stream>>>(
          yb, woT_l, bo + (size_t)l * DM, nullptr, x, DM, DM / 2, DM, DM / 256);
      ln_kernel<0><<<MR / 4, 256, 0, stream>>>(x, nullptr, ln2w + l * DM, ln2b + l * DM, h);
    }

    gemm8<1, 1, 1><<<dim3(D4 / 256, MR / 256, 1), 512, 0, stream>>>(
        h, fcT_l, bfc + (size_t)l * D4, ub, nullptr, D4, DM, DM, D4 / 256);

    if (slab) {
      gemm8<2, 2, 0><<<dim3(DM / 256, MR / 256, 2), 512, 0, stream>>>(
          ub, prT_l, bproj + (size_t)l * DM, slabP, nullptr, DM, D4 / 2, D4, DM / 256);
    } else {
      gemm8<2, 2, 1><<<dim3(DM / 256, MR / 256, 2), 512, 0, stream>>>(
          ub, prT_l, bproj + (size_t)l * DM, nullptr, x, DM, D4 / 2, D4, DM / 256);
    }
  }

  if (slab)
    pooled_kernel<1><<<dim3(12, NB), 256, 0, stream>>>(x, slabP, lnfw, lnfb, dw, db, pooled);
  else
    pooled_kernel<0><<<dim3(12, NB), 256, 0, stream>>>(x, nullptr, lnfw, lnfb, dw, db, pooled);
  logits_kernel<<<1, 64, 0, stream>>>(pooled, hw, hb, out);
}